// Round 4
// baseline (1071.249 us; speedup 1.0000x reference)
//
#include <hip/hip_runtime.h>
#include <cstddef>
#include <cstdint>

#define EPS_F 1e-7f
#define MAX_NORM_F 0.99999f   // (1 - 1e-5) / SC, SC = 1

typedef __attribute__((ext_vector_type(8))) short bf16x8;  // 8 bf16 (4 VGPR)
typedef __attribute__((ext_vector_type(4))) float f32x4;

// ---------------------------------------------------------------- helpers
__device__ __forceinline__ unsigned short f2bf(float x) {
  unsigned int u = __float_as_uint(x);
  unsigned int r = u + 0x7FFFu + ((u >> 16) & 1u);   // RNE (no NaN in data)
  return (unsigned short)(r >> 16);
}
__device__ __forceinline__ float bf2f(unsigned short h) {
  return __uint_as_float(((unsigned int)h) << 16);
}

__device__ __forceinline__ float wave_sum(float v) {
#pragma unroll
  for (int off = 32; off; off >>= 1) v += __shfl_xor(v, off);
  return v;
}

__device__ __forceinline__ float block_sum(float v, float* red) {
  const int lane = threadIdx.x & 63;
  const int w = threadIdx.x >> 6;
  v = wave_sum(v);
  __syncthreads();
  if (lane == 0) red[w] = v;
  __syncthreads();
  return red[0] + red[1] + red[2] + red[3];
}

__device__ __forceinline__ void store_split4(unsigned short* H, unsigned short* L,
                                             size_t idx, float4 v) {
  ushort4 h, l;
  h.x = f2bf(v.x); l.x = f2bf(v.x - bf2f(h.x));
  h.y = f2bf(v.y); l.y = f2bf(v.y - bf2f(h.y));
  h.z = f2bf(v.z); l.z = f2bf(v.z - bf2f(h.z));
  h.w = f2bf(v.w); l.w = f2bf(v.w - bf2f(h.w));
  *reinterpret_cast<ushort4*>(H + idx) = h;
  *reinterpret_cast<ushort4*>(L + idx) = l;
}

// --------------------------------------------- weight transpose+split pass
// W [K][N] fp32 -> Th/Tl [N][Kp] bf16 (hi, lo), zero-padded for k >= K.
__global__ __launch_bounds__(256) void wsplit_k(
    const float* __restrict__ W, unsigned short* __restrict__ Th,
    unsigned short* __restrict__ Tl, int K, int N, int Kp)
{
  __shared__ float T[64][65];
  const int n0 = blockIdx.x * 64, k0 = blockIdx.y * 64;
  const int t = threadIdx.x;
  {
    const int lk = t >> 2;
    const int ln = (t & 3) * 16;
    const int gk = k0 + lk;
#pragma unroll
    for (int j = 0; j < 16; j += 4) {
      float4 v = make_float4(0.f, 0.f, 0.f, 0.f);
      const int gn = n0 + ln + j;
      if (gk < K) {
        if (gn + 3 < N) {
          v = *reinterpret_cast<const float4*>(W + (size_t)gk * N + gn);
        } else {
          const float* p = W + (size_t)gk * N;
          if (gn     < N) v.x = p[gn];
          if (gn + 1 < N) v.y = p[gn + 1];
          if (gn + 2 < N) v.z = p[gn + 2];
          if (gn + 3 < N) v.w = p[gn + 3];
        }
      }
      T[lk][ln + j + 0] = v.x; T[lk][ln + j + 1] = v.y;
      T[lk][ln + j + 2] = v.z; T[lk][ln + j + 3] = v.w;
    }
  }
  __syncthreads();
  {
    const int rn = t >> 2;
    const int rk = (t & 3) * 16;
    const int gn = n0 + rn;
    if (gn < N) {
      size_t base = (size_t)gn * Kp + k0 + rk;
#pragma unroll
      for (int j = 0; j < 16; ++j) {
        float x = T[rk + j][rn];
        unsigned short h = f2bf(x);
        unsigned short l = f2bf(x - bf2f(h));
        Th[base + j] = h;
        Tl[base + j] = l;
      }
    }
  }
}

// --------------------------------------------------------- bf16x3 MFMA GEMM
// acc += Ah*Bh + Ah*Bl + Al*Bh. 16x16x32 bf16 MFMA.
// All variants: 2-phase reg-staged double-buffered K-loop, 1 barrier/iter.
#define LDAB 40   // LDS row stride in bf16 (80B: 16B-aligned, ~2-way banks)

// ---- variant 1: 128x128 tile, pre-split A, fp32 out, partial-K blockIdx.z
__global__ __launch_bounds__(256, 2) void gemm_x3_pre(
    const unsigned short* __restrict__ Ah, const unsigned short* __restrict__ Al,
    int lda,
    const unsigned short* __restrict__ Bh, const unsigned short* __restrict__ Bl,
    int ldb,
    const float* __restrict__ bias, float* __restrict__ C, int ldc,
    int M, int N, int Ktot, int kslice, int relu)
{
  __shared__ unsigned short sAh[2][128 * LDAB];
  __shared__ unsigned short sAl[2][128 * LDAB];
  __shared__ unsigned short sBh[2][128 * LDAB];
  __shared__ unsigned short sBl[2][128 * LDAB];

  const int t = threadIdx.x;
  const int bm = blockIdx.x * 128;
  const int bn = blockIdx.y * 128;
  const int z  = blockIdx.z;
  const int koff = z * kslice;
  const int klen = min(kslice, Ktot - koff);
  float* Cz = C + (size_t)z * (size_t)M * (size_t)N;

  const int lane = t & 63, wave = t >> 6;
  const int wm = (wave >> 1) * 64, wn = (wave & 1) * 64;
  const int fr = lane & 15, kg = lane >> 4;

  const int srow = t >> 1, cpair = t & 1;
  const size_t abase = (size_t)(bm + srow) * lda + koff + cpair * 16;
  const int brow = bn + srow;
  const bool bval = brow < N;
  const size_t bbase = (size_t)(bval ? brow : 0) * ldb + koff + cpair * 16;
  const int di = srow * LDAB + cpair * 16;

  int4 ra0, ra1, ra2, ra3, rb0, rb1, rb2, rb3;
  const int4 z4 = make_int4(0, 0, 0, 0);
  auto load_tile = [&](int k0) {
    ra0 = *reinterpret_cast<const int4*>(Ah + abase + k0);
    ra1 = *reinterpret_cast<const int4*>(Ah + abase + k0 + 8);
    ra2 = *reinterpret_cast<const int4*>(Al + abase + k0);
    ra3 = *reinterpret_cast<const int4*>(Al + abase + k0 + 8);
    rb0 = bval ? *reinterpret_cast<const int4*>(Bh + bbase + k0)     : z4;
    rb1 = bval ? *reinterpret_cast<const int4*>(Bh + bbase + k0 + 8) : z4;
    rb2 = bval ? *reinterpret_cast<const int4*>(Bl + bbase + k0)     : z4;
    rb3 = bval ? *reinterpret_cast<const int4*>(Bl + bbase + k0 + 8) : z4;
  };

  f32x4 acc[4][4] = {};
  load_tile(0);
  int cur = 0;

  for (int k0 = 0; k0 < klen; k0 += 32) {
    *reinterpret_cast<int4*>(&sAh[cur][di])     = ra0;
    *reinterpret_cast<int4*>(&sAh[cur][di + 8]) = ra1;
    *reinterpret_cast<int4*>(&sAl[cur][di])     = ra2;
    *reinterpret_cast<int4*>(&sAl[cur][di + 8]) = ra3;
    *reinterpret_cast<int4*>(&sBh[cur][di])     = rb0;
    *reinterpret_cast<int4*>(&sBh[cur][di + 8]) = rb1;
    *reinterpret_cast<int4*>(&sBl[cur][di])     = rb2;
    *reinterpret_cast<int4*>(&sBl[cur][di + 8]) = rb3;
    __syncthreads();
    const int kn = (k0 + 32 < klen) ? (k0 + 32) : k0;
    load_tile(kn);                    // prefetch next tile (waited at next write)

    bf16x8 fah[4], fal[4], fbh[4], fbl[4];
#pragma unroll
    for (int i = 0; i < 4; ++i) {
      const int ar = wm + i * 16 + fr;
      fah[i] = *reinterpret_cast<const bf16x8*>(&sAh[cur][ar * LDAB + kg * 8]);
      fal[i] = *reinterpret_cast<const bf16x8*>(&sAl[cur][ar * LDAB + kg * 8]);
      const int br = wn + i * 16 + fr;
      fbh[i] = *reinterpret_cast<const bf16x8*>(&sBh[cur][br * LDAB + kg * 8]);
      fbl[i] = *reinterpret_cast<const bf16x8*>(&sBl[cur][br * LDAB + kg * 8]);
    }
#pragma unroll
    for (int mi = 0; mi < 4; ++mi)
#pragma unroll
      for (int ni = 0; ni < 4; ++ni) {
        acc[mi][ni] = __builtin_amdgcn_mfma_f32_16x16x32_bf16(
            fah[mi], fbh[ni], acc[mi][ni], 0, 0, 0);
        acc[mi][ni] = __builtin_amdgcn_mfma_f32_16x16x32_bf16(
            fah[mi], fbl[ni], acc[mi][ni], 0, 0, 0);
        acc[mi][ni] = __builtin_amdgcn_mfma_f32_16x16x32_bf16(
            fal[mi], fbh[ni], acc[mi][ni], 0, 0, 0);
      }
    cur ^= 1;
  }

#pragma unroll
  for (int mi = 0; mi < 4; ++mi) {
#pragma unroll
    for (int ni = 0; ni < 4; ++ni) {
      const int col = bn + wn + ni * 16 + fr;
      if (col >= N) continue;
      const int row0 = bm + wm + mi * 16 + kg * 4;
      const float bv = bias ? bias[col] : 0.f;
#pragma unroll
      for (int r = 0; r < 4; ++r) {
        float v = acc[mi][ni][r] + bv;
        if (relu) v = fmaxf(v, 0.f);
        Cz[(size_t)(row0 + r) * ldc + col] = v;
      }
    }
  }
}

// ---- variant 2: 128x64 tile, pre-split A, bias+relu+bf16-split epilogue.
// Requires M%128==0, N%64==0, K%32==0. Full K per block (no split).
__global__ __launch_bounds__(256, 2) void gemm_x3_n64(
    const unsigned short* __restrict__ Ah, const unsigned short* __restrict__ Al,
    int lda,
    const unsigned short* __restrict__ Bh, const unsigned short* __restrict__ Bl,
    int ldb,
    const float* __restrict__ bias,
    unsigned short* __restrict__ Ch, unsigned short* __restrict__ Cl,
    int ldc, int K, int relu)
{
  __shared__ unsigned short sAh[2][128 * LDAB];
  __shared__ unsigned short sAl[2][128 * LDAB];
  __shared__ unsigned short sBh[2][64 * LDAB];
  __shared__ unsigned short sBl[2][64 * LDAB];

  const int t = threadIdx.x;
  const int bm = blockIdx.x * 128;
  const int bn = blockIdx.y * 64;
  const int lane = t & 63, wave = t >> 6;
  const int wm = (wave >> 1) * 64, wn = (wave & 1) * 32;
  const int fr = lane & 15, kg = lane >> 4;

  const int srow = t >> 1, cpair = t & 1;
  const size_t abase = (size_t)(bm + srow) * lda + cpair * 16;
  const int dia = srow * LDAB + cpair * 16;
  const int srB = t >> 2, ckB = (t & 3) * 8;
  const size_t bbase = (size_t)(bn + srB) * ldb + ckB;
  const int dib = srB * LDAB + ckB;

  int4 ra0, ra1, ra2, ra3, rb0, rb1;
  auto load_tile = [&](int k0) {
    ra0 = *reinterpret_cast<const int4*>(Ah + abase + k0);
    ra1 = *reinterpret_cast<const int4*>(Ah + abase + k0 + 8);
    ra2 = *reinterpret_cast<const int4*>(Al + abase + k0);
    ra3 = *reinterpret_cast<const int4*>(Al + abase + k0 + 8);
    rb0 = *reinterpret_cast<const int4*>(Bh + bbase + k0);
    rb1 = *reinterpret_cast<const int4*>(Bl + bbase + k0);
  };

  f32x4 acc[4][2] = {};
  load_tile(0);
  int cur = 0;

  for (int k0 = 0; k0 < K; k0 += 32) {
    *reinterpret_cast<int4*>(&sAh[cur][dia])     = ra0;
    *reinterpret_cast<int4*>(&sAh[cur][dia + 8]) = ra1;
    *reinterpret_cast<int4*>(&sAl[cur][dia])     = ra2;
    *reinterpret_cast<int4*>(&sAl[cur][dia + 8]) = ra3;
    *reinterpret_cast<int4*>(&sBh[cur][dib])     = rb0;
    *reinterpret_cast<int4*>(&sBl[cur][dib])     = rb1;
    __syncthreads();
    const int kn = (k0 + 32 < K) ? (k0 + 32) : k0;
    load_tile(kn);

    bf16x8 fah[4], fal[4], fbh[2], fbl[2];
#pragma unroll
    for (int i = 0; i < 4; ++i) {
      const int ar = wm + i * 16 + fr;
      fah[i] = *reinterpret_cast<const bf16x8*>(&sAh[cur][ar * LDAB + kg * 8]);
      fal[i] = *reinterpret_cast<const bf16x8*>(&sAl[cur][ar * LDAB + kg * 8]);
    }
#pragma unroll
    for (int i = 0; i < 2; ++i) {
      const int br = wn + i * 16 + fr;
      fbh[i] = *reinterpret_cast<const bf16x8*>(&sBh[cur][br * LDAB + kg * 8]);
      fbl[i] = *reinterpret_cast<const bf16x8*>(&sBl[cur][br * LDAB + kg * 8]);
    }
#pragma unroll
    for (int mi = 0; mi < 4; ++mi)
#pragma unroll
      for (int ni = 0; ni < 2; ++ni) {
        acc[mi][ni] = __builtin_amdgcn_mfma_f32_16x16x32_bf16(
            fah[mi], fbh[ni], acc[mi][ni], 0, 0, 0);
        acc[mi][ni] = __builtin_amdgcn_mfma_f32_16x16x32_bf16(
            fah[mi], fbl[ni], acc[mi][ni], 0, 0, 0);
        acc[mi][ni] = __builtin_amdgcn_mfma_f32_16x16x32_bf16(
            fal[mi], fbh[ni], acc[mi][ni], 0, 0, 0);
      }
    cur ^= 1;
  }

#pragma unroll
  for (int mi = 0; mi < 4; ++mi) {
#pragma unroll
    for (int ni = 0; ni < 2; ++ni) {
      const int col = bn + wn + ni * 16 + fr;
      const int row0 = bm + wm + mi * 16 + kg * 4;
      const float bv = bias[col];
#pragma unroll
      for (int r = 0; r < 4; ++r) {
        float v = acc[mi][ni][r] + bv;
        if (relu) v = fmaxf(v, 0.f);
        const size_t o = (size_t)(row0 + r) * ldc + col;
        unsigned short h = f2bf(v);
        Ch[o] = h;
        Cl[o] = f2bf(v - bf2f(h));
      }
    }
  }
}

// ---- variant 3: embed GEMM, fp32 A (contiguous 504-float segment rows),
// blockIdx.z = component. M=15360, N=256, K=504, Kp=512.
__global__ __launch_bounds__(256, 2) void gemm_x3_embed(
    const float* __restrict__ A0, const float* __restrict__ A1,
    const float* __restrict__ A2, const float* __restrict__ A3,
    const unsigned short* __restrict__ EW, const float* __restrict__ b_embed,
    float* __restrict__ TAN)
{
  __shared__ unsigned short sAh[2][128 * LDAB];
  __shared__ unsigned short sAl[2][128 * LDAB];
  __shared__ unsigned short sBh[2][128 * LDAB];
  __shared__ unsigned short sBl[2][128 * LDAB];

  const int c = blockIdx.z;
  const float* A = (c == 0) ? A0 : (c == 1) ? A1 : (c == 2) ? A2 : A3;
  const unsigned short* Bh = EW + (size_t)c * 262144u;
  const unsigned short* Bl = Bh + 131072u;
  const float* bias = b_embed + c * 256;
  float* C = TAN + (size_t)c * 15360 * 256;

  const int t = threadIdx.x;
  const int bm = blockIdx.x * 128;
  const int bn = blockIdx.y * 128;
  const int lane = t & 63, wave = t >> 6;
  const int wm = (wave >> 1) * 64, wn = (wave & 1) * 64;
  const int fr = lane & 15, kg = lane >> 4;

  const int srow = t >> 1, cpair = t & 1;
  const float* aptr = A + (size_t)(bm + srow) * 504 + cpair * 16;
  const size_t bbase = (size_t)(bn + srow) * 512 + cpair * 16;
  const int di = srow * LDAB + cpair * 16;

  float4 fa0, fa1, fa2, fa3;
  int4 rb0, rb1, rb2, rb3;
  const float4 zf = make_float4(0.f, 0.f, 0.f, 0.f);
  auto load_tile = [&](int k0) {
    const int gk = k0 + cpair * 16;
    fa0 = (gk      < 504) ? *reinterpret_cast<const float4*>(aptr + k0)      : zf;
    fa1 = (gk + 4  < 504) ? *reinterpret_cast<const float4*>(aptr + k0 + 4)  : zf;
    fa2 = (gk + 8  < 504) ? *reinterpret_cast<const float4*>(aptr + k0 + 8)  : zf;
    fa3 = (gk + 12 < 504) ? *reinterpret_cast<const float4*>(aptr + k0 + 12) : zf;
    rb0 = *reinterpret_cast<const int4*>(Bh + bbase + k0);
    rb1 = *reinterpret_cast<const int4*>(Bh + bbase + k0 + 8);
    rb2 = *reinterpret_cast<const int4*>(Bl + bbase + k0);
    rb3 = *reinterpret_cast<const int4*>(Bl + bbase + k0 + 8);
  };

  f32x4 acc[4][4] = {};
  load_tile(0);
  int cur = 0;

  for (int k0 = 0; k0 < 512; k0 += 32) {
    {  // convert fp32 regs -> split bf16, write LDS
      float xs[16] = {fa0.x, fa0.y, fa0.z, fa0.w, fa1.x, fa1.y, fa1.z, fa1.w,
                      fa2.x, fa2.y, fa2.z, fa2.w, fa3.x, fa3.y, fa3.z, fa3.w};
      unsigned short ah[16], al[16];
#pragma unroll
      for (int i = 0; i < 16; ++i) {
        unsigned short h = f2bf(xs[i]);
        ah[i] = h;
        al[i] = f2bf(xs[i] - bf2f(h));
      }
      bf16x8 p;
#pragma unroll
      for (int i = 0; i < 8; ++i) p[i] = (short)ah[i];
      *reinterpret_cast<bf16x8*>(&sAh[cur][di]) = p;
#pragma unroll
      for (int i = 0; i < 8; ++i) p[i] = (short)ah[8 + i];
      *reinterpret_cast<bf16x8*>(&sAh[cur][di + 8]) = p;
#pragma unroll
      for (int i = 0; i < 8; ++i) p[i] = (short)al[i];
      *reinterpret_cast<bf16x8*>(&sAl[cur][di]) = p;
#pragma unroll
      for (int i = 0; i < 8; ++i) p[i] = (short)al[8 + i];
      *reinterpret_cast<bf16x8*>(&sAl[cur][di + 8]) = p;
      *reinterpret_cast<int4*>(&sBh[cur][di])     = rb0;
      *reinterpret_cast<int4*>(&sBh[cur][di + 8]) = rb1;
      *reinterpret_cast<int4*>(&sBl[cur][di])     = rb2;
      *reinterpret_cast<int4*>(&sBl[cur][di + 8]) = rb3;
    }
    __syncthreads();
    const int kn = (k0 + 32 < 512) ? (k0 + 32) : k0;
    load_tile(kn);

    bf16x8 fah[4], fal[4], fbh[4], fbl[4];
#pragma unroll
    for (int i = 0; i < 4; ++i) {
      const int ar = wm + i * 16 + fr;
      fah[i] = *reinterpret_cast<const bf16x8*>(&sAh[cur][ar * LDAB + kg * 8]);
      fal[i] = *reinterpret_cast<const bf16x8*>(&sAl[cur][ar * LDAB + kg * 8]);
      const int br = wn + i * 16 + fr;
      fbh[i] = *reinterpret_cast<const bf16x8*>(&sBh[cur][br * LDAB + kg * 8]);
      fbl[i] = *reinterpret_cast<const bf16x8*>(&sBl[cur][br * LDAB + kg * 8]);
    }
#pragma unroll
    for (int mi = 0; mi < 4; ++mi)
#pragma unroll
      for (int ni = 0; ni < 4; ++ni) {
        acc[mi][ni] = __builtin_amdgcn_mfma_f32_16x16x32_bf16(
            fah[mi], fbh[ni], acc[mi][ni], 0, 0, 0);
        acc[mi][ni] = __builtin_amdgcn_mfma_f32_16x16x32_bf16(
            fah[mi], fbl[ni], acc[mi][ni], 0, 0, 0);
        acc[mi][ni] = __builtin_amdgcn_mfma_f32_16x16x32_bf16(
            fal[mi], fbh[ni], acc[mi][ni], 0, 0, 0);
      }
    cur ^= 1;
  }

#pragma unroll
  for (int mi = 0; mi < 4; ++mi) {
#pragma unroll
    for (int ni = 0; ni < 4; ++ni) {
      const int col = bn + wn + ni * 16 + fr;
      const int row0 = bm + wm + mi * 16 + kg * 4;
      const float bv = bias[col];
#pragma unroll
      for (int r = 0; r < 4; ++r)
        C[(size_t)(row0 + r) * 256 + col] = acc[mi][ni][r] + bv;
    }
  }
}

// ------------------------------------------------- LayerNorm + expmap0 -> Z
__global__ __launch_bounds__(256) void ln_expmap0_k(
    const float* __restrict__ TAN, const float* __restrict__ gamma,
    const float* __restrict__ beta, float* __restrict__ Z)
{
  __shared__ float red[4];
  const int row = blockIdx.x;     // b*30 + n
  const int d = threadIdx.x;
  const int b = row / 30;
  const int n = row % 30;

  float tc[4];
  float tsum = 0.f;
#pragma unroll
  for (int c = 0; c < 4; ++c) {
    float x = TAN[((size_t)c * 15360 + row) * 256 + d];
    float mu = block_sum(x, red) * (1.f / 256.f);
    float xm = x - mu;
    float var = block_sum(xm * xm, red) * (1.f / 256.f);
    float tv = xm * rsqrtf(var + 1e-5f) * gamma[c * 256 + d] + beta[c * 256 + d];
    tc[c] = tv;
    tsum += tv;
  }
#pragma unroll
  for (int g = 0; g < 5; ++g) {
    float v = (g == 0) ? tsum : tc[g - 1];
    float n2 = block_sum(v * v, red);
    float nn = fmaxf(sqrtf(n2), EPS_F);
    float th = tanhf(nn);
    float w = v * (th / nn);
    if (th > MAX_NORM_F) w *= MAX_NORM_F / fmaxf(th, EPS_F);
    Z[(((size_t)g * 512 + b) * 38 + n) * 256 + d] = w;
  }
}

// ------------------------------------------------ per-pair logmap (1 wave)
__device__ __forceinline__ float4 pair_log(const float* zr, int c, int lane) {
  float4 x = *reinterpret_cast<const float4*>(zr + (size_t)c * 256 + lane * 4);
  float4 y = *reinterpret_cast<const float4*>(zr + (size_t)(c + 1) * 256 + lane * 4);
  float x2 = wave_sum(x.x * x.x + x.y * x.y + x.z * x.z + x.w * x.w);
  float y2 = wave_sum(y.x * y.x + y.y * y.y + y.z * y.z + y.w * y.w);
  float xy = wave_sum(x.x * y.x + x.y * y.y + x.z * y.z + x.w * y.w);
  float a  = 1.f - 2.f * xy + y2;
  float bb = 1.f - x2;
  float den = fmaxf(1.f - 2.f * xy + x2 * y2, EPS_F);
  float inv = 1.f / den;
  float4 u;
  u.x = (bb * y.x - a * x.x) * inv;
  u.y = (bb * y.y - a * x.y) * inv;
  u.z = (bb * y.z - a * x.z) * inv;
  u.w = (bb * y.w - a * x.w) * inv;
  float u2 = wave_sum(u.x * u.x + u.y * u.y + u.z * u.z + u.w * u.w);
  float un = fmaxf(sqrtf(u2), EPS_F);
  float coef = fmaxf(1.f - x2, EPS_F) * atanhf(fminf(un, 1.f - 1e-7f)) / un;
  float4 o;
  o.x = coef * u.x; o.y = coef * u.y; o.z = coef * u.z; o.w = coef * u.w;
  return o;
}

__device__ __forceinline__ float4 logmap0_col(const float* zr, int c, int lane) {
  float4 z = *reinterpret_cast<const float4*>(zr + (size_t)c * 256 + lane * 4);
  float z2 = wave_sum(z.x * z.x + z.y * z.y + z.z * z.z + z.w * z.w);
  float nz = fmaxf(sqrtf(z2), EPS_F);
  float cc = atanhf(fminf(nz, 1.f - 1e-7f)) / nz;
  float4 o;
  o.x = cc * z.x; o.y = cc * z.y; o.z = cc * z.z; o.w = cc * z.w;
  return o;
}

// -------------------------- velocity (incremental) + feat (split bf16 out)
__global__ __launch_bounds__(256) void vel_feat_inc_k(
    const float* __restrict__ Z, unsigned short* __restrict__ Fh,
    unsigned short* __restrict__ Fl, float* __restrict__ VSUM, int t)
{
  const int r = blockIdx.x * 4 + (threadIdx.x >> 6);
  const int lane = threadIdx.x & 63;
  const float* zr = Z + (size_t)r * 38 * 256;

  float4 vs;
  if (t == 0) {
    vs = make_float4(0.f, 0.f, 0.f, 0.f);
#pragma unroll 1
    for (int j = 0; j < 29; ++j) {
      float4 p = pair_log(zr, j, lane);
      vs.x += p.x; vs.y += p.y; vs.z += p.z; vs.w += p.w;
    }
  } else {
    vs = *reinterpret_cast<const float4*>(VSUM + (size_t)r * 256 + lane * 4);
    float4 pm = pair_log(zr, t - 1, lane);
    float4 pp = pair_log(zr, t + 28, lane);
    vs.x += pp.x - pm.x; vs.y += pp.y - pm.y;
    vs.z += pp.z - pm.z; vs.w += pp.w - pm.w;
  }
  *reinterpret_cast<float4*>(VSUM + (size_t)r * 256 + lane * 4) = vs;

  float4 fl = logmap0_col(zr, t + 29, lane);   // z_last
  float4 fp = logmap0_col(zr, t + 28, lane);   // z_prev
  const size_t fb = (size_t)r * 768 + lane * 4;
  store_split4(Fh, Fl, fb, fl);
  store_split4(Fh, Fl, fb + 256, fp);
  const float s29 = 1.f / 29.f;
  float4 o;
  o.x = vs.x * s29; o.y = vs.y * s29; o.z = vs.z * s29; o.w = vs.w * s29;
  store_split4(Fh, Fl, fb + 512, o);
}

// ----------------------- z_next = expmap(z_last, sum(V parts) + b3)
__global__ __launch_bounds__(256) void expmap_step_k(
    float* __restrict__ Z, const float* __restrict__ VP,
    const float* __restrict__ b3, int t)
{
  const int r = blockIdx.x * 4 + (threadIdx.x >> 6);
  const int lane = threadIdx.x & 63;
  float* zr = Z + (size_t)r * 38 * 256;
  float4 x = *reinterpret_cast<const float4*>(zr + (size_t)(t + 29) * 256 + lane * 4);
  float4 v = *reinterpret_cast<const float4*>(b3 + lane * 4);
#pragma unroll
  for (int p = 0; p < 8; ++p) {
    float4 a = *reinterpret_cast<const float4*>(
        VP + (size_t)p * 655360u + (size_t)r * 256 + lane * 4);
    v.x += a.x; v.y += a.y; v.z += a.z; v.w += a.w;
  }
  float x2 = wave_sum(x.x * x.x + x.y * x.y + x.z * x.z + x.w * x.w);
  float v2 = wave_sum(v.x * v.x + v.y * v.y + v.z * v.z + v.w * v.w);
  float xv = wave_sum(x.x * v.x + x.y * v.y + x.z * v.z + x.w * v.w);

  float vn = fmaxf(sqrtf(v2), EPS_F);
  float lamx = 2.f / fmaxf(1.f - x2, EPS_F);
  float s = tanhf(0.5f * lamx * vn) / vn;
  float xy = s * xv;
  float y2 = s * s * v2;
  float a  = 1.f + 2.f * xy + y2;
  float bb = 1.f - x2;
  float den = fmaxf(1.f + 2.f * xy + x2 * y2, EPS_F);
  float inv = 1.f / den;
  float4 res;
  res.x = (a * x.x + bb * s * v.x) * inv;
  res.y = (a * x.y + bb * s * v.y) * inv;
  res.z = (a * x.z + bb * s * v.z) * inv;
  res.w = (a * x.w + bb * s * v.w) * inv;
  float r2 = wave_sum(res.x * res.x + res.y * res.y + res.z * res.z + res.w * res.w);
  float rn = sqrtf(r2);
  if (rn > MAX_NORM_F) {
    float sc = MAX_NORM_F / fmaxf(rn, EPS_F);
    res.x *= sc; res.y *= sc; res.z *= sc; res.w *= sc;
  }
  *reinterpret_cast<float4*>(zr + (size_t)(t + 30) * 256 + lane * 4) = res;
}

// -------------------------- logmap0 over appended cols, split bf16 out
__global__ __launch_bounds__(256) void logmap0_rows_k(
    const float* __restrict__ Z, unsigned short* __restrict__ Uh,
    unsigned short* __restrict__ Ul)
{
  const int q = blockIdx.x * 4 + (threadIdx.x >> 6);
  const int lane = threadIdx.x & 63;
  const int r = q >> 3;
  const int tt = q & 7;
  float4 o = logmap0_col(Z + (size_t)r * 38 * 256, 30 + tt, lane);
  store_split4(Uh, Ul, (size_t)q * 256 + lane * 4, o);
}

// ---------------------------------------------------------------- launcher
extern "C" void kernel_launch(void* const* d_in, const int* in_sizes, int n_in,
                              void* d_out, int out_size, void* d_ws, size_t ws_size,
                              hipStream_t stream)
{
  const float* c0 = (const float*)d_in[0];
  const float* c1 = (const float*)d_in[1];
  const float* c2 = (const float*)d_in[2];
  const float* c3 = (const float*)d_in[3];
  const float* W_embed = (const float*)d_in[4];
  const float* b_embed = (const float*)d_in[5];
  const float* ln_g    = (const float*)d_in[6];
  const float* ln_b    = (const float*)d_in[7];
  const float* W1 = (const float*)d_in[8];
  const float* b1 = (const float*)d_in[9];
  const float* W2 = (const float*)d_in[10];
  const float* b2 = (const float*)d_in[11];
  const float* W3 = (const float*)d_in[12];
  const float* b3 = (const float*)d_in[13];
  const float* W_out = (const float*)d_in[14];
  const float* b_out = (const float*)d_in[15];
  float* out = (float*)d_out;
  float* ws  = (float*)d_ws;

  // ---- ws layout (floats). Peak = Z(24,903,680) + R(15,728,640) = 162.5 MB.
  float* Z = ws;
  float* TAN = ws + 24903680u;                      // R region = TAN in stage A
  unsigned short* Rs = (unsigned short*)(ws + 24903680u);
  unsigned short* W1h = Rs;                         // [1024][768]
  unsigned short* W1l = Rs + 786432u;
  unsigned short* W2h = Rs + 1572864u;              // [1024][1024]
  unsigned short* W2l = Rs + 2621440u;
  unsigned short* W3h = Rs + 3670016u;              // [256][1024]
  unsigned short* W3l = Rs + 3932160u;
  unsigned short* Woh = Rs + 4194304u;              // [504][256]
  unsigned short* Wol = Rs + 4323328u;
  unsigned short* FEATh = Rs + 4452352u;            // [2560][768]
  unsigned short* FEATl = Rs + 6418432u;
  unsigned short* H1h = Rs + 8384512u;              // [2560][1024]
  unsigned short* H1l = Rs + 11005952u;
  unsigned short* H2h = Rs + 13627392u;             // [2560][1024]
  unsigned short* H2l = Rs + 16248832u;             // ends @ short 18,870,272
  float* VP   = ws + 34338816u;                     // 8 x 2560*256 parts
  float* VSUM = ws + 39581696u;                     // 2560*256
  unsigned short* Uh = Rs + 4452352u;               // stage C, reuses FEAT/H1
  unsigned short* Ul = Rs + 9695232u;

  // ---- d_out scratch: embed weights (stage A only; final GEMM overwrites).
  unsigned short* EW = (unsigned short*)d_out;      // 4 x (h 131072 | l 131072)

  dim3 blk(256);

  // Stage A: embed weight split -> embed GEMM (z-fused) -> LN+expmap0
  for (int c = 0; c < 4; ++c) {
    unsigned short* h = EW + (size_t)c * 262144u;
    wsplit_k<<<dim3(4, 8), blk, 0, stream>>>(
        W_embed + (size_t)c * 504 * 256, h, h + 131072u, 504, 256, 512);
  }
  gemm_x3_embed<<<dim3(120, 2, 4), blk, 0, stream>>>(
      c0, c1, c2, c3, EW, b_embed, TAN);
  ln_expmap0_k<<<dim3(15360), blk, 0, stream>>>(TAN, ln_g, ln_b, Z);

  // MLP/out weight splits (TAN dead now)
  wsplit_k<<<dim3(16, 12), blk, 0, stream>>>(W1, W1h, W1l, 768, 1024, 768);
  wsplit_k<<<dim3(16, 16), blk, 0, stream>>>(W2, W2h, W2l, 1024, 1024, 1024);
  wsplit_k<<<dim3(4, 16),  blk, 0, stream>>>(W3, W3h, W3l, 1024, 256, 1024);
  wsplit_k<<<dim3(8, 4),   blk, 0, stream>>>(W_out, Woh, Wol, 256, 504, 256);

  // Stage B: 8 recurrent steps
  for (int t = 0; t < 8; ++t) {
    vel_feat_inc_k<<<dim3(640), blk, 0, stream>>>(Z, FEATh, FEATl, VSUM, t);
    gemm_x3_n64<<<dim3(20, 16), blk, 0, stream>>>(
        FEATh, FEATl, 768, W1h, W1l, 768, b1, H1h, H1l, 1024, 768, 1);
    gemm_x3_n64<<<dim3(20, 16), blk, 0, stream>>>(
        H1h, H1l, 1024, W2h, W2l, 1024, b2, H2h, H2l, 1024, 1024, 1);
    gemm_x3_pre<<<dim3(20, 2, 8), blk, 0, stream>>>(
        H2h, H2l, 1024, W3h, W3l, 1024, nullptr, VP, 256,
        2560, 256, 1024, 128, 0);
    expmap_step_k<<<dim3(640), blk, 0, stream>>>(Z, VP, b3, t);
  }

  // Stage C: logmap0 -> final projection into d_out
  logmap0_rows_k<<<dim3(5120), blk, 0, stream>>>(Z, Uh, Ul);
  gemm_x3_pre<<<dim3(160, 4, 1), blk, 0, stream>>>(
      Uh, Ul, 256, Woh, Wol, 256, b_out, out, 504,
      20480, 504, 256, 256, 0);
}

// Round 5
// 963.018 us; speedup vs baseline: 1.1124x; 1.1124x over previous
//
#include <hip/hip_runtime.h>
#include <cstddef>
#include <cstdint>

#define EPS_F 1e-7f
#define MAX_NORM_F 0.99999f   // (1 - 1e-5) / SC, SC = 1

typedef __attribute__((ext_vector_type(8))) short bf16x8;  // 8 bf16 (4 VGPR)
typedef __attribute__((ext_vector_type(4))) float f32x4;

// ---------------------------------------------------------------- helpers
__device__ __forceinline__ unsigned short f2bf(float x) {
  unsigned int u = __float_as_uint(x);
  unsigned int r = u + 0x7FFFu + ((u >> 16) & 1u);   // RNE (no NaN in data)
  return (unsigned short)(r >> 16);
}
__device__ __forceinline__ float bf2f(unsigned short h) {
  return __uint_as_float(((unsigned int)h) << 16);
}

__device__ __forceinline__ float wave_sum(float v) {
#pragma unroll
  for (int off = 32; off; off >>= 1) v += __shfl_xor(v, off);
  return v;
}

__device__ __forceinline__ void store_split4(unsigned short* H, unsigned short* L,
                                             size_t idx, float4 v) {
  ushort4 h, l;
  h.x = f2bf(v.x); l.x = f2bf(v.x - bf2f(h.x));
  h.y = f2bf(v.y); l.y = f2bf(v.y - bf2f(h.y));
  h.z = f2bf(v.z); l.z = f2bf(v.z - bf2f(h.z));
  h.w = f2bf(v.w); l.w = f2bf(v.w - bf2f(h.w));
  *reinterpret_cast<ushort4*>(H + idx) = h;
  *reinterpret_cast<ushort4*>(L + idx) = l;
}

// async global->LDS, 16B per lane; LDS dest = uniform base + lane*16
__device__ __forceinline__ void gl_lds16(const unsigned short* g, unsigned short* l) {
  __builtin_amdgcn_global_load_lds(
      (const __attribute__((address_space(1))) void*)g,
      (__attribute__((address_space(3))) void*)l, 16, 0, 0);
}

// --------------------------------------------- weight transpose+split pass
// W [K][N] fp32 -> Th/Tl [N][Kp] bf16 (hi, lo), zero-padded for k >= K.
// Fused over up to 4 matrices via blockIdx.z descriptor.
struct WS4 {
  const float* W[4];
  unsigned short* Th[4];
  unsigned short* Tl[4];
  int K[4], N[4], Kp[4];
};

__global__ __launch_bounds__(256) void wsplit_all_k(WS4 d) {
  const int zi = blockIdx.z;
  const float* W = d.W[zi];
  unsigned short* Th = d.Th[zi];
  unsigned short* Tl = d.Tl[zi];
  const int K = d.K[zi], N = d.N[zi], Kp = d.Kp[zi];
  const int n0 = blockIdx.x * 64, k0 = blockIdx.y * 64;
  if (n0 >= N || k0 >= Kp) return;

  __shared__ float T[64][65];
  const int t = threadIdx.x;
  {
    const int lk = t >> 2;
    const int ln = (t & 3) * 16;
    const int gk = k0 + lk;
#pragma unroll
    for (int j = 0; j < 16; j += 4) {
      float4 v = make_float4(0.f, 0.f, 0.f, 0.f);
      const int gn = n0 + ln + j;
      if (gk < K) {
        if (gn + 3 < N) {
          v = *reinterpret_cast<const float4*>(W + (size_t)gk * N + gn);
        } else {
          const float* p = W + (size_t)gk * N;
          if (gn     < N) v.x = p[gn];
          if (gn + 1 < N) v.y = p[gn + 1];
          if (gn + 2 < N) v.z = p[gn + 2];
          if (gn + 3 < N) v.w = p[gn + 3];
        }
      }
      T[lk][ln + j + 0] = v.x; T[lk][ln + j + 1] = v.y;
      T[lk][ln + j + 2] = v.z; T[lk][ln + j + 3] = v.w;
    }
  }
  __syncthreads();
  {
    const int rn = t >> 2;
    const int rk = (t & 3) * 16;
    const int gn = n0 + rn;
    if (gn < N) {
      size_t base = (size_t)gn * Kp + k0 + rk;
#pragma unroll
      for (int j = 0; j < 16; ++j) {
        float x = T[rk + j][rn];
        unsigned short h = f2bf(x);
        unsigned short l = f2bf(x - bf2f(h));
        Th[base + j] = h;
        Tl[base + j] = l;
      }
    }
  }
}

// --------------------------------------------------------- bf16x3 MFMA GEMM
// acc += Ah*Bh + Ah*Bl + Al*Bh. 16x16x32 bf16 MFMA. m97 structure:
// single-buffered linear LDS tiles [128][32] bf16, global_load_lds staging
// with per-lane source k-chunk XOR (chunk ^= (row>>1)&3), fragment ds_read
// with the same XOR (2-way banks, free). 2 barriers / K-iter; occupancy
// (3-5 blocks/CU) hides the drain.

// fragment read offset (elements) for logical row r, k-group kg, tile base tb
__device__ __forceinline__ int frag_off(int tb, int r, int kg) {
  return tb + r * 32 + ((kg ^ ((r >> 1) & 3)) << 3);
}

// ---- variant 1: 128x128 tile, pre-split A, fp32 out, partial-K blockIdx.z
__global__ __launch_bounds__(256) void gemm_x3_pre(
    const unsigned short* __restrict__ Ah, const unsigned short* __restrict__ Al,
    int lda,
    const unsigned short* __restrict__ Bh, const unsigned short* __restrict__ Bl,
    int ldb,
    const float* __restrict__ bias, float* __restrict__ C, int ldc,
    int M, int N, int Ktot, int kslice, int relu)
{
  __shared__ unsigned short sm[16384];   // Ah@0 Al@4096 Bh@8192 Bl@12288

  const int t = threadIdx.x;
  const int bm = blockIdx.x * 128;
  const int bn = blockIdx.y * 128;
  const int z  = blockIdx.z;
  const int koff = z * kslice;
  const int klen = min(kslice, Ktot - koff);
  float* Cz = C + (size_t)z * (size_t)M * (size_t)N;

  const int lane = t & 63, wave = t >> 6;
  const int wm = (wave >> 1) * 64, wn = (wave & 1) * 64;
  const int fr = lane & 15, kg = lane >> 4;

  // staging: 32 wave-issues (8 per tile); wave w takes j = w + 4q, q=0..7
  const unsigned short* sp[8];
  unsigned short* dp[8];
#pragma unroll
  for (int q = 0; q < 8; ++q) {
    const int j = wave + 4 * q;
    const int tile = j >> 3;            // 0 Ah, 1 Al, 2 Bh, 3 Bl
    const int i = j & 7;
    const int row = i * 16 + (lane >> 2);
    const int lchunk = lane & 3;
    const int chunk = lchunk ^ ((row >> 1) & 3);
    const unsigned short* base = (tile == 0) ? Ah : (tile == 1) ? Al
                               : (tile == 2) ? Bh : Bl;
    const int ld = (tile < 2) ? lda : ldb;
    int grow = (tile < 2) ? (bm + row) : min(bn + row, N - 1);
    sp[q] = base + (size_t)grow * ld + koff + chunk * 8;
    dp[q] = sm + tile * 4096 + i * 512 + lane * 8;
  }

  // fragment offsets (k0-invariant)
  int offA[4], offB[4];
#pragma unroll
  for (int i = 0; i < 4; ++i) {
    offA[i] = frag_off(0,    wm + i * 16 + fr, kg);
    offB[i] = frag_off(8192, wn + i * 16 + fr, kg);
  }

  f32x4 acc[4][4] = {};

  for (int k0 = 0; k0 < klen; k0 += 32) {
#pragma unroll
    for (int q = 0; q < 8; ++q) { gl_lds16(sp[q], dp[q]); sp[q] += 32; }
    __syncthreads();   // drains vmcnt (loads) before reads

    bf16x8 fbh[4], fbl[4];
#pragma unroll
    for (int ni = 0; ni < 4; ++ni) {
      fbh[ni] = *reinterpret_cast<const bf16x8*>(sm + offB[ni]);
      fbl[ni] = *reinterpret_cast<const bf16x8*>(sm + offB[ni] + 4096);
    }
#pragma unroll
    for (int mi = 0; mi < 4; ++mi) {
      bf16x8 ah = *reinterpret_cast<const bf16x8*>(sm + offA[mi]);
      bf16x8 al = *reinterpret_cast<const bf16x8*>(sm + offA[mi] + 4096);
#pragma unroll
      for (int ni = 0; ni < 4; ++ni) {
        acc[mi][ni] = __builtin_amdgcn_mfma_f32_16x16x32_bf16(ah, fbh[ni], acc[mi][ni], 0, 0, 0);
        acc[mi][ni] = __builtin_amdgcn_mfma_f32_16x16x32_bf16(ah, fbl[ni], acc[mi][ni], 0, 0, 0);
        acc[mi][ni] = __builtin_amdgcn_mfma_f32_16x16x32_bf16(al, fbh[ni], acc[mi][ni], 0, 0, 0);
      }
    }
    __syncthreads();   // reads done before next stage overwrites
  }

#pragma unroll
  for (int mi = 0; mi < 4; ++mi) {
#pragma unroll
    for (int ni = 0; ni < 4; ++ni) {
      const int col = bn + wn + ni * 16 + fr;
      if (col >= N) continue;
      const int row0 = bm + wm + mi * 16 + kg * 4;
      const float bv = bias ? bias[col] : 0.f;
#pragma unroll
      for (int r = 0; r < 4; ++r) {
        float v = acc[mi][ni][r] + bv;
        if (relu) v = fmaxf(v, 0.f);
        Cz[(size_t)(row0 + r) * ldc + col] = v;
      }
    }
  }
}

// ---- variant 2: 128x64 tile, pre-split A, bias+relu+bf16-split epilogue.
// Requires M%128==0, N%64==0, K%32==0.
__global__ __launch_bounds__(256) void gemm_x3_n64(
    const unsigned short* __restrict__ Ah, const unsigned short* __restrict__ Al,
    int lda,
    const unsigned short* __restrict__ Bh, const unsigned short* __restrict__ Bl,
    int ldb,
    const float* __restrict__ bias,
    unsigned short* __restrict__ Ch, unsigned short* __restrict__ Cl,
    int ldc, int K, int relu)
{
  __shared__ unsigned short sm[12288];   // Ah@0 Al@4096 Bh@8192 Bl@10240

  const int t = threadIdx.x;
  const int bm = blockIdx.x * 128;
  const int bn = blockIdx.y * 64;
  const int lane = t & 63, wave = t >> 6;
  const int wm = (wave >> 1) * 64, wn = (wave & 1) * 32;
  const int fr = lane & 15, kg = lane >> 4;

  // 24 wave-issues: j<8 Ah, j<16 Al, j<20 Bh, j<24 Bl; wave w: j = w + 4q
  const unsigned short* sp[6];
  unsigned short* dp[6];
#pragma unroll
  for (int q = 0; q < 6; ++q) {
    const int j = wave + 4 * q;
    int tile, i;
    if (j < 8)       { tile = 0; i = j; }
    else if (j < 16) { tile = 1; i = j - 8; }
    else if (j < 20) { tile = 2; i = j - 16; }
    else             { tile = 3; i = j - 20; }
    const int row = i * 16 + (lane >> 2);
    const int chunk = (lane & 3) ^ ((row >> 1) & 3);
    const unsigned short* base = (tile == 0) ? Ah : (tile == 1) ? Al
                               : (tile == 2) ? Bh : Bl;
    const int ld = (tile < 2) ? lda : ldb;
    const int grow = (tile < 2) ? (bm + row) : (bn + row);
    const int tb = (tile == 0) ? 0 : (tile == 1) ? 4096 : (tile == 2) ? 8192 : 10240;
    sp[q] = base + (size_t)grow * ld + chunk * 8;
    dp[q] = sm + tb + i * 512 + lane * 8;
  }

  int offA[4], offB[2];
#pragma unroll
  for (int i = 0; i < 4; ++i) offA[i] = frag_off(0, wm + i * 16 + fr, kg);
#pragma unroll
  for (int i = 0; i < 2; ++i) offB[i] = frag_off(8192, wn + i * 16 + fr, kg);

  f32x4 acc[4][2] = {};

  for (int k0 = 0; k0 < K; k0 += 32) {
#pragma unroll
    for (int q = 0; q < 6; ++q) { gl_lds16(sp[q], dp[q]); sp[q] += 32; }
    __syncthreads();

    bf16x8 fbh[2], fbl[2];
#pragma unroll
    for (int ni = 0; ni < 2; ++ni) {
      fbh[ni] = *reinterpret_cast<const bf16x8*>(sm + offB[ni]);
      fbl[ni] = *reinterpret_cast<const bf16x8*>(sm + offB[ni] + 2048);
    }
#pragma unroll
    for (int mi = 0; mi < 4; ++mi) {
      bf16x8 ah = *reinterpret_cast<const bf16x8*>(sm + offA[mi]);
      bf16x8 al = *reinterpret_cast<const bf16x8*>(sm + offA[mi] + 4096);
#pragma unroll
      for (int ni = 0; ni < 2; ++ni) {
        acc[mi][ni] = __builtin_amdgcn_mfma_f32_16x16x32_bf16(ah, fbh[ni], acc[mi][ni], 0, 0, 0);
        acc[mi][ni] = __builtin_amdgcn_mfma_f32_16x16x32_bf16(ah, fbl[ni], acc[mi][ni], 0, 0, 0);
        acc[mi][ni] = __builtin_amdgcn_mfma_f32_16x16x32_bf16(al, fbh[ni], acc[mi][ni], 0, 0, 0);
      }
    }
    __syncthreads();
  }

#pragma unroll
  for (int mi = 0; mi < 4; ++mi) {
#pragma unroll
    for (int ni = 0; ni < 2; ++ni) {
      const int col = bn + wn + ni * 16 + fr;
      const int row0 = bm + wm + mi * 16 + kg * 4;
      const float bv = bias[col];
#pragma unroll
      for (int r = 0; r < 4; ++r) {
        float v = acc[mi][ni][r] + bv;
        if (relu) v = fmaxf(v, 0.f);
        const size_t o = (size_t)(row0 + r) * ldc + col;
        unsigned short h = f2bf(v);
        Ch[o] = h;
        Cl[o] = f2bf(v - bf2f(h));
      }
    }
  }
}

// ---- variant 3: embed GEMM. A = fp32 (contiguous 504-float segment rows),
// reg-staged + converted to split bf16 with swizzled ds_write; B via
// global_load_lds. blockIdx.z = component. M=15360, N=256, K=504, Kp=512.
__global__ __launch_bounds__(256) void gemm_x3_embed(
    const float* __restrict__ A0, const float* __restrict__ A1,
    const float* __restrict__ A2, const float* __restrict__ A3,
    const unsigned short* __restrict__ EW, const float* __restrict__ b_embed,
    float* __restrict__ TAN)
{
  __shared__ unsigned short sm[16384];   // Ah@0 Al@4096 Bh@8192 Bl@12288

  const int c = blockIdx.z;
  const float* A = (c == 0) ? A0 : (c == 1) ? A1 : (c == 2) ? A2 : A3;
  const unsigned short* Bh = EW + (size_t)c * 262144u;
  const unsigned short* Bl = Bh + 131072u;
  const float* bias = b_embed + c * 256;
  float* C = TAN + (size_t)c * 15360 * 256;

  const int t = threadIdx.x;
  const int bm = blockIdx.x * 128;
  const int bn = blockIdx.y * 128;
  const int lane = t & 63, wave = t >> 6;
  const int wm = (wave >> 1) * 64, wn = (wave & 1) * 64;
  const int fr = lane & 15, kg = lane >> 4;

  // B staging: 16 wave-issues; wave w: j = w + 4q, q=0..3
  const unsigned short* sp[4];
  unsigned short* dp[4];
#pragma unroll
  for (int q = 0; q < 4; ++q) {
    const int j = wave + 4 * q;
    const int tile = j >> 3;            // 0 Bh, 1 Bl
    const int i = j & 7;
    const int row = i * 16 + (lane >> 2);
    const int chunk = (lane & 3) ^ ((row >> 1) & 3);
    const unsigned short* base = tile ? Bl : Bh;
    sp[q] = base + (size_t)(bn + row) * 512 + chunk * 8;
    dp[q] = sm + 8192 + tile * 4096 + i * 512 + lane * 8;
  }

  // A staging: thread t -> row t>>1, khalf t&1 (16 fp32)
  const int arow = t >> 1, khalf = t & 1;
  const float* aptr = A + (size_t)(bm + arow) * 504 + khalf * 16;
  const int axor = (arow >> 1) & 3;
  // two logical chunks c0 = khalf*2, c1 = khalf*2+1
  const int woff0 = arow * 32 + (((khalf * 2)     ^ axor) << 3);
  const int woff1 = arow * 32 + (((khalf * 2 + 1) ^ axor) << 3);

  int offA[4], offB[4];
#pragma unroll
  for (int i = 0; i < 4; ++i) {
    offA[i] = frag_off(0,    wm + i * 16 + fr, kg);
    offB[i] = frag_off(8192, wn + i * 16 + fr, kg);
  }

  f32x4 acc[4][4] = {};

  for (int k0 = 0; k0 < 512; k0 += 32) {
#pragma unroll
    for (int q = 0; q < 4; ++q) { gl_lds16(sp[q], dp[q]); sp[q] += 32; }
    {  // A: load fp32, split, swizzled ds_write
      const float4 zf = make_float4(0.f, 0.f, 0.f, 0.f);
      const int gk = k0 + khalf * 16;
      float4 f0 = (gk      < 504) ? *reinterpret_cast<const float4*>(aptr + k0)      : zf;
      float4 f1 = (gk + 4  < 504) ? *reinterpret_cast<const float4*>(aptr + k0 + 4)  : zf;
      float4 f2 = (gk + 8  < 504) ? *reinterpret_cast<const float4*>(aptr + k0 + 8)  : zf;
      float4 f3 = (gk + 12 < 504) ? *reinterpret_cast<const float4*>(aptr + k0 + 12) : zf;
      float xs[16] = {f0.x, f0.y, f0.z, f0.w, f1.x, f1.y, f1.z, f1.w,
                      f2.x, f2.y, f2.z, f2.w, f3.x, f3.y, f3.z, f3.w};
      unsigned short ah[16], al[16];
#pragma unroll
      for (int i = 0; i < 16; ++i) {
        unsigned short h = f2bf(xs[i]);
        ah[i] = h;
        al[i] = f2bf(xs[i] - bf2f(h));
      }
      bf16x8 p;
#pragma unroll
      for (int i = 0; i < 8; ++i) p[i] = (short)ah[i];
      *reinterpret_cast<bf16x8*>(sm + woff0) = p;
#pragma unroll
      for (int i = 0; i < 8; ++i) p[i] = (short)ah[8 + i];
      *reinterpret_cast<bf16x8*>(sm + woff1) = p;
#pragma unroll
      for (int i = 0; i < 8; ++i) p[i] = (short)al[i];
      *reinterpret_cast<bf16x8*>(sm + 4096 + woff0) = p;
#pragma unroll
      for (int i = 0; i < 8; ++i) p[i] = (short)al[8 + i];
      *reinterpret_cast<bf16x8*>(sm + 4096 + woff1) = p;
    }
    __syncthreads();

    bf16x8 fbh[4], fbl[4];
#pragma unroll
    for (int ni = 0; ni < 4; ++ni) {
      fbh[ni] = *reinterpret_cast<const bf16x8*>(sm + offB[ni]);
      fbl[ni] = *reinterpret_cast<const bf16x8*>(sm + offB[ni] + 4096);
    }
#pragma unroll
    for (int mi = 0; mi < 4; ++mi) {
      bf16x8 ah = *reinterpret_cast<const bf16x8*>(sm + offA[mi]);
      bf16x8 al = *reinterpret_cast<const bf16x8*>(sm + offA[mi] + 4096);
#pragma unroll
      for (int ni = 0; ni < 4; ++ni) {
        acc[mi][ni] = __builtin_amdgcn_mfma_f32_16x16x32_bf16(ah, fbh[ni], acc[mi][ni], 0, 0, 0);
        acc[mi][ni] = __builtin_amdgcn_mfma_f32_16x16x32_bf16(ah, fbl[ni], acc[mi][ni], 0, 0, 0);
        acc[mi][ni] = __builtin_amdgcn_mfma_f32_16x16x32_bf16(al, fbh[ni], acc[mi][ni], 0, 0, 0);
      }
    }
    __syncthreads();
  }

#pragma unroll
  for (int mi = 0; mi < 4; ++mi) {
#pragma unroll
    for (int ni = 0; ni < 4; ++ni) {
      const int col = bn + wn + ni * 16 + fr;   // < 256 always
      const int row0 = bm + wm + mi * 16 + kg * 4;
      const float bv = bias[col];
#pragma unroll
      for (int r = 0; r < 4; ++r)
        C[(size_t)(row0 + r) * 256 + col] = acc[mi][ni][r] + bv;
    }
  }
}

// ------------------------------------- LayerNorm + expmap0 -> Z (wave/row)
__global__ __launch_bounds__(256) void ln_expmap0_k(
    const float* __restrict__ TAN, const float* __restrict__ gamma,
    const float* __restrict__ beta, float* __restrict__ Z)
{
  const int row = blockIdx.x * 4 + (threadIdx.x >> 6);   // b*30 + n
  const int lane = threadIdx.x & 63;
  const int b = row / 30;
  const int n = row % 30;

  float4 tc[4];
  float4 ts = make_float4(0.f, 0.f, 0.f, 0.f);
#pragma unroll
  for (int c = 0; c < 4; ++c) {
    float4 x = *reinterpret_cast<const float4*>(
        TAN + ((size_t)c * 15360 + row) * 256 + lane * 4);
    float mu = wave_sum(x.x + x.y + x.z + x.w) * (1.f / 256.f);
    float4 xm = make_float4(x.x - mu, x.y - mu, x.z - mu, x.w - mu);
    float var = wave_sum(xm.x * xm.x + xm.y * xm.y + xm.z * xm.z + xm.w * xm.w)
                * (1.f / 256.f);
    float rs = rsqrtf(var + 1e-5f);
    float4 g = *reinterpret_cast<const float4*>(gamma + c * 256 + lane * 4);
    float4 be = *reinterpret_cast<const float4*>(beta + c * 256 + lane * 4);
    float4 tv = make_float4(xm.x * rs * g.x + be.x, xm.y * rs * g.y + be.y,
                            xm.z * rs * g.z + be.z, xm.w * rs * g.w + be.w);
    tc[c] = tv;
    ts.x += tv.x; ts.y += tv.y; ts.z += tv.z; ts.w += tv.w;
  }
#pragma unroll
  for (int g5 = 0; g5 < 5; ++g5) {
    float4 v = (g5 == 0) ? ts : tc[g5 - 1];
    float n2 = wave_sum(v.x * v.x + v.y * v.y + v.z * v.z + v.w * v.w);
    float nn = fmaxf(sqrtf(n2), EPS_F);
    float th = tanhf(nn);
    float w = th / nn;
    if (th > MAX_NORM_F) w *= MAX_NORM_F / fmaxf(th, EPS_F);
    float4 o = make_float4(v.x * w, v.y * w, v.z * w, v.w * w);
    *reinterpret_cast<float4*>(
        Z + (((size_t)g5 * 512 + b) * 38 + n) * 256 + lane * 4) = o;
  }
}

// ------------------------------------------------ per-pair logmap (1 wave)
__device__ __forceinline__ float4 pair_log(const float* zr, int c, int lane) {
  float4 x = *reinterpret_cast<const float4*>(zr + (size_t)c * 256 + lane * 4);
  float4 y = *reinterpret_cast<const float4*>(zr + (size_t)(c + 1) * 256 + lane * 4);
  float x2 = wave_sum(x.x * x.x + x.y * x.y + x.z * x.z + x.w * x.w);
  float y2 = wave_sum(y.x * y.x + y.y * y.y + y.z * y.z + y.w * y.w);
  float xy = wave_sum(x.x * y.x + x.y * y.y + x.z * y.z + x.w * y.w);
  float a  = 1.f - 2.f * xy + y2;
  float bb = 1.f - x2;
  float den = fmaxf(1.f - 2.f * xy + x2 * y2, EPS_F);
  float inv = 1.f / den;
  float4 u;
  u.x = (bb * y.x - a * x.x) * inv;
  u.y = (bb * y.y - a * x.y) * inv;
  u.z = (bb * y.z - a * x.z) * inv;
  u.w = (bb * y.w - a * x.w) * inv;
  float u2 = wave_sum(u.x * u.x + u.y * u.y + u.z * u.z + u.w * u.w);
  float un = fmaxf(sqrtf(u2), EPS_F);
  float coef = fmaxf(1.f - x2, EPS_F) * atanhf(fminf(un, 1.f - 1e-7f)) / un;
  float4 o;
  o.x = coef * u.x; o.y = coef * u.y; o.z = coef * u.z; o.w = coef * u.w;
  return o;
}

__device__ __forceinline__ float4 logmap0_col(const float* zr, int c, int lane) {
  float4 z = *reinterpret_cast<const float4*>(zr + (size_t)c * 256 + lane * 4);
  float z2 = wave_sum(z.x * z.x + z.y * z.y + z.z * z.z + z.w * z.w);
  float nz = fmaxf(sqrtf(z2), EPS_F);
  float cc = atanhf(fminf(nz, 1.f - 1e-7f)) / nz;
  float4 o;
  o.x = cc * z.x; o.y = cc * z.y; o.z = cc * z.z; o.w = cc * z.w;
  return o;
}

// -------------------------- velocity (incremental) + feat (split bf16 out)
__global__ __launch_bounds__(256) void vel_feat_inc_k(
    const float* __restrict__ Z, unsigned short* __restrict__ Fh,
    unsigned short* __restrict__ Fl, float* __restrict__ VSUM, int t)
{
  const int r = blockIdx.x * 4 + (threadIdx.x >> 6);
  const int lane = threadIdx.x & 63;
  const float* zr = Z + (size_t)r * 38 * 256;

  float4 vs;
  if (t == 0) {
    vs = make_float4(0.f, 0.f, 0.f, 0.f);
#pragma unroll 1
    for (int j = 0; j < 29; ++j) {
      float4 p = pair_log(zr, j, lane);
      vs.x += p.x; vs.y += p.y; vs.z += p.z; vs.w += p.w;
    }
  } else {
    vs = *reinterpret_cast<const float4*>(VSUM + (size_t)r * 256 + lane * 4);
    float4 pm = pair_log(zr, t - 1, lane);
    float4 pp = pair_log(zr, t + 28, lane);
    vs.x += pp.x - pm.x; vs.y += pp.y - pm.y;
    vs.z += pp.z - pm.z; vs.w += pp.w - pm.w;
  }
  *reinterpret_cast<float4*>(VSUM + (size_t)r * 256 + lane * 4) = vs;

  float4 fl = logmap0_col(zr, t + 29, lane);   // z_last
  float4 fp = logmap0_col(zr, t + 28, lane);   // z_prev
  const size_t fb = (size_t)r * 768 + lane * 4;
  store_split4(Fh, Fl, fb, fl);
  store_split4(Fh, Fl, fb + 256, fp);
  const float s29 = 1.f / 29.f;
  float4 o;
  o.x = vs.x * s29; o.y = vs.y * s29; o.z = vs.z * s29; o.w = vs.w * s29;
  store_split4(Fh, Fl, fb + 512, o);
}

// ----------------------- z_next = expmap(z_last, sum(V parts) + b3)
__global__ __launch_bounds__(256) void expmap_step_k(
    float* __restrict__ Z, const float* __restrict__ VP,
    const float* __restrict__ b3, int t)
{
  const int r = blockIdx.x * 4 + (threadIdx.x >> 6);
  const int lane = threadIdx.x & 63;
  float* zr = Z + (size_t)r * 38 * 256;
  float4 x = *reinterpret_cast<const float4*>(zr + (size_t)(t + 29) * 256 + lane * 4);
  float4 v = *reinterpret_cast<const float4*>(b3 + lane * 4);
#pragma unroll
  for (int p = 0; p < 8; ++p) {
    float4 a = *reinterpret_cast<const float4*>(
        VP + (size_t)p * 655360u + (size_t)r * 256 + lane * 4);
    v.x += a.x; v.y += a.y; v.z += a.z; v.w += a.w;
  }
  float x2 = wave_sum(x.x * x.x + x.y * x.y + x.z * x.z + x.w * x.w);
  float v2 = wave_sum(v.x * v.x + v.y * v.y + v.z * v.z + v.w * v.w);
  float xv = wave_sum(x.x * v.x + x.y * v.y + x.z * v.z + x.w * v.w);

  float vn = fmaxf(sqrtf(v2), EPS_F);
  float lamx = 2.f / fmaxf(1.f - x2, EPS_F);
  float s = tanhf(0.5f * lamx * vn) / vn;
  float xy = s * xv;
  float y2 = s * s * v2;
  float a  = 1.f + 2.f * xy + y2;
  float bb = 1.f - x2;
  float den = fmaxf(1.f + 2.f * xy + x2 * y2, EPS_F);
  float inv = 1.f / den;
  float4 res;
  res.x = (a * x.x + bb * s * v.x) * inv;
  res.y = (a * x.y + bb * s * v.y) * inv;
  res.z = (a * x.z + bb * s * v.z) * inv;
  res.w = (a * x.w + bb * s * v.w) * inv;
  float r2 = wave_sum(res.x * res.x + res.y * res.y + res.z * res.z + res.w * res.w);
  float rn = sqrtf(r2);
  if (rn > MAX_NORM_F) {
    float sc = MAX_NORM_F / fmaxf(rn, EPS_F);
    res.x *= sc; res.y *= sc; res.z *= sc; res.w *= sc;
  }
  *reinterpret_cast<float4*>(zr + (size_t)(t + 30) * 256 + lane * 4) = res;
}

// -------------------------- logmap0 over appended cols, split bf16 out
__global__ __launch_bounds__(256) void logmap0_rows_k(
    const float* __restrict__ Z, unsigned short* __restrict__ Uh,
    unsigned short* __restrict__ Ul)
{
  const int q = blockIdx.x * 4 + (threadIdx.x >> 6);
  const int lane = threadIdx.x & 63;
  const int r = q >> 3;
  const int tt = q & 7;
  float4 o = logmap0_col(Z + (size_t)r * 38 * 256, 30 + tt, lane);
  store_split4(Uh, Ul, (size_t)q * 256 + lane * 4, o);
}

// ---------------------------------------------------------------- launcher
extern "C" void kernel_launch(void* const* d_in, const int* in_sizes, int n_in,
                              void* d_out, int out_size, void* d_ws, size_t ws_size,
                              hipStream_t stream)
{
  const float* c0 = (const float*)d_in[0];
  const float* c1 = (const float*)d_in[1];
  const float* c2 = (const float*)d_in[2];
  const float* c3 = (const float*)d_in[3];
  const float* W_embed = (const float*)d_in[4];
  const float* b_embed = (const float*)d_in[5];
  const float* ln_g    = (const float*)d_in[6];
  const float* ln_b    = (const float*)d_in[7];
  const float* W1 = (const float*)d_in[8];
  const float* b1 = (const float*)d_in[9];
  const float* W2 = (const float*)d_in[10];
  const float* b2 = (const float*)d_in[11];
  const float* W3 = (const float*)d_in[12];
  const float* b3 = (const float*)d_in[13];
  const float* W_out = (const float*)d_in[14];
  const float* b_out = (const float*)d_in[15];
  float* out = (float*)d_out;
  float* ws  = (float*)d_ws;

  // ---- ws layout (floats). Peak = Z(24,903,680) + R(15,728,640) = 162.5 MB.
  float* Z = ws;
  float* TAN = ws + 24903680u;                      // R region = TAN in stage A
  unsigned short* Rs = (unsigned short*)(ws + 24903680u);
  unsigned short* W1h = Rs;                         // [1024][768]
  unsigned short* W1l = Rs + 786432u;
  unsigned short* W2h = Rs + 1572864u;              // [1024][1024]
  unsigned short* W2l = Rs + 2621440u;
  unsigned short* W3h = Rs + 3670016u;              // [256][1024]
  unsigned short* W3l = Rs + 3932160u;
  unsigned short* Woh = Rs + 4194304u;              // [504][256]
  unsigned short* Wol = Rs + 4323328u;
  unsigned short* FEATh = Rs + 4452352u;            // [2560][768]
  unsigned short* FEATl = Rs + 6418432u;
  unsigned short* H1h = Rs + 8384512u;              // [2560][1024]
  unsigned short* H1l = Rs + 11005952u;
  unsigned short* H2h = Rs + 13627392u;             // [2560][1024]
  unsigned short* H2l = Rs + 16248832u;             // ends @ short 18,870,272
  float* VP   = ws + 34338816u;                     // 8 x 2560*256 parts
  float* VSUM = ws + 39581696u;                     // 2560*256
  unsigned short* Uh = Rs + 4452352u;               // stage C, reuses FEAT/H1
  unsigned short* Ul = Rs + 9695232u;

  // ---- d_out scratch: embed weights (stage A only; final GEMM overwrites).
  unsigned short* EW = (unsigned short*)d_out;      // 4 x (h 131072 | l 131072)

  dim3 blk(256);

  // Stage A: embed weight split (one launch) -> embed GEMM -> LN+expmap0
  {
    WS4 d;
    for (int c = 0; c < 4; ++c) {
      d.W[c] = W_embed + (size_t)c * 504 * 256;
      d.Th[c] = EW + (size_t)c * 262144u;
      d.Tl[c] = EW + (size_t)c * 262144u + 131072u;
      d.K[c] = 504; d.N[c] = 256; d.Kp[c] = 512;
    }
    wsplit_all_k<<<dim3(4, 8, 4), blk, 0, stream>>>(d);
  }
  gemm_x3_embed<<<dim3(120, 2, 4), blk, 0, stream>>>(
      c0, c1, c2, c3, EW, b_embed, TAN);
  ln_expmap0_k<<<dim3(3840), blk, 0, stream>>>(TAN, ln_g, ln_b, Z);

  // MLP/out weight splits in one launch (TAN dead now)
  {
    WS4 d;
    d.W[0] = W1;    d.Th[0] = W1h; d.Tl[0] = W1l; d.K[0] = 768;  d.N[0] = 1024; d.Kp[0] = 768;
    d.W[1] = W2;    d.Th[1] = W2h; d.Tl[1] = W2l; d.K[1] = 1024; d.N[1] = 1024; d.Kp[1] = 1024;
    d.W[2] = W3;    d.Th[2] = W3h; d.Tl[2] = W3l; d.K[2] = 1024; d.N[2] = 256;  d.Kp[2] = 1024;
    d.W[3] = W_out; d.Th[3] = Woh; d.Tl[3] = Wol; d.K[3] = 256;  d.N[3] = 504;  d.Kp[3] = 256;
    wsplit_all_k<<<dim3(16, 16, 4), blk, 0, stream>>>(d);
  }

  // Stage B: 8 recurrent steps
  for (int t = 0; t < 8; ++t) {
    vel_feat_inc_k<<<dim3(640), blk, 0, stream>>>(Z, FEATh, FEATl, VSUM, t);
    gemm_x3_n64<<<dim3(20, 16), blk, 0, stream>>>(
        FEATh, FEATl, 768, W1h, W1l, 768, b1, H1h, H1l, 1024, 768, 1);
    gemm_x3_n64<<<dim3(20, 16), blk, 0, stream>>>(
        H1h, H1l, 1024, W2h, W2l, 1024, b2, H2h, H2l, 1024, 1024, 1);
    gemm_x3_pre<<<dim3(20, 2, 8), blk, 0, stream>>>(
        H2h, H2l, 1024, W3h, W3l, 1024, nullptr, VP, 256,
        2560, 256, 1024, 128, 0);
    expmap_step_k<<<dim3(640), blk, 0, stream>>>(Z, VP, b3, t);
  }

  // Stage C: logmap0 -> final projection into d_out
  logmap0_rows_k<<<dim3(5120), blk, 0, stream>>>(Z, Uh, Ul);
  gemm_x3_pre<<<dim3(160, 4, 1), blk, 0, stream>>>(
      Uh, Ul, 256, Woh, Wol, 256, b_out, out, 504,
      20480, 504, 256, 256, 0);
}

// Round 6
// 842.680 us; speedup vs baseline: 1.2712x; 1.1428x over previous
//
#include <hip/hip_runtime.h>
#include <cstddef>
#include <cstdint>

#define EPS_F 1e-7f
#define MAX_NORM_F 0.99999f   // (1 - 1e-5) / SC, SC = 1

typedef __attribute__((ext_vector_type(8))) short bf16x8;  // 8 bf16 (4 VGPR)
typedef __attribute__((ext_vector_type(4))) float f32x4;

// ---------------------------------------------------------------- helpers
__device__ __forceinline__ unsigned short f2bf(float x) {
  unsigned int u = __float_as_uint(x);
  unsigned int r = u + 0x7FFFu + ((u >> 16) & 1u);   // RNE (no NaN in data)
  return (unsigned short)(r >> 16);
}
__device__ __forceinline__ float bf2f(unsigned short h) {
  return __uint_as_float(((unsigned int)h) << 16);
}

__device__ __forceinline__ float wave_sum(float v) {
#pragma unroll
  for (int off = 32; off; off >>= 1) v += __shfl_xor(v, off);
  return v;
}

__device__ __forceinline__ void store_split4(unsigned short* H, unsigned short* L,
                                             size_t idx, float4 v) {
  ushort4 h, l;
  h.x = f2bf(v.x); l.x = f2bf(v.x - bf2f(h.x));
  h.y = f2bf(v.y); l.y = f2bf(v.y - bf2f(h.y));
  h.z = f2bf(v.z); l.z = f2bf(v.z - bf2f(h.z));
  h.w = f2bf(v.w); l.w = f2bf(v.w - bf2f(h.w));
  *reinterpret_cast<ushort4*>(H + idx) = h;
  *reinterpret_cast<ushort4*>(L + idx) = l;
}

// async global->LDS, 16B per lane; LDS dest = uniform base + lane*16
__device__ __forceinline__ void gl_lds16(const unsigned short* g, unsigned short* l) {
  __builtin_amdgcn_global_load_lds(
      (const __attribute__((address_space(1))) void*)g,
      (__attribute__((address_space(3))) void*)l, 16, 0, 0);
}

// --------------------------------------------- weight transpose+split pass
struct WS4 {
  const float* W[4];
  unsigned short* Th[4];
  unsigned short* Tl[4];
  int K[4], N[4], Kp[4];
};

__global__ __launch_bounds__(256) void wsplit_all_k(WS4 d) {
  const int zi = blockIdx.z;
  const float* W = d.W[zi];
  unsigned short* Th = d.Th[zi];
  unsigned short* Tl = d.Tl[zi];
  const int K = d.K[zi], N = d.N[zi], Kp = d.Kp[zi];
  const int n0 = blockIdx.x * 64, k0 = blockIdx.y * 64;
  if (n0 >= N || k0 >= Kp) return;

  __shared__ float T[64][65];
  const int t = threadIdx.x;
  {
    const int lk = t >> 2;
    const int ln = (t & 3) * 16;
    const int gk = k0 + lk;
#pragma unroll
    for (int j = 0; j < 16; j += 4) {
      float4 v = make_float4(0.f, 0.f, 0.f, 0.f);
      const int gn = n0 + ln + j;
      if (gk < K) {
        if (gn + 3 < N) {
          v = *reinterpret_cast<const float4*>(W + (size_t)gk * N + gn);
        } else {
          const float* p = W + (size_t)gk * N;
          if (gn     < N) v.x = p[gn];
          if (gn + 1 < N) v.y = p[gn + 1];
          if (gn + 2 < N) v.z = p[gn + 2];
          if (gn + 3 < N) v.w = p[gn + 3];
        }
      }
      T[lk][ln + j + 0] = v.x; T[lk][ln + j + 1] = v.y;
      T[lk][ln + j + 2] = v.z; T[lk][ln + j + 3] = v.w;
    }
  }
  __syncthreads();
  {
    const int rn = t >> 2;
    const int rk = (t & 3) * 16;
    const int gn = n0 + rn;
    if (gn < N) {
      size_t base = (size_t)gn * Kp + k0 + rk;
#pragma unroll
      for (int j = 0; j < 16; ++j) {
        float x = T[rk + j][rn];
        unsigned short h = f2bf(x);
        unsigned short l = f2bf(x - bf2f(h));
        Th[base + j] = h;
        Tl[base + j] = l;
      }
    }
  }
}

// --------------------------------------------------------- bf16x3 MFMA GEMM
// acc += Ah*Bh + Ah*Bl + Al*Bh. 16x16x32 bf16 MFMA.
// Double-buffered LDS, 1 barrier/K-iter, prefetch issued BEFORE compute:
//   prologue: STAGE(buf0,k0)
//   iter: barrier (buf[cur] ready) -> STAGE(buf^1,k+1) -> MFMA(buf[cur])
// Linear LDS + k-chunk XOR swizzle (src and frag-read both XOR (row>>1)&3).

__device__ __forceinline__ int frag_off(int tb, int r, int kg) {
  return tb + r * 32 + ((kg ^ ((r >> 1) & 3)) << 3);
}

// ---- core: 128x128 tile, pre-split A, fp32 out. sm = 2 x 16384 shorts.
__device__ __forceinline__ void gemm128_dbuf(
    unsigned short* sm,
    const unsigned short* Ah, const unsigned short* Al, int lda,
    const unsigned short* Bh, const unsigned short* Bl, int ldb,
    const float* bias, float* C, int ldc,
    int N, int klen, int relu, int bm, int bn)
{
  const int t = threadIdx.x;
  const int lane = t & 63, wave = t >> 6;
  const int wm = (wave >> 1) * 64, wn = (wave & 1) * 64;
  const int fr = lane & 15, kg = lane >> 4;

  const unsigned short* sp[8];
  int dpo[8];
#pragma unroll
  for (int q = 0; q < 8; ++q) {
    const int j = wave + 4 * q;
    const int tile = j >> 3;            // 0 Ah, 1 Al, 2 Bh, 3 Bl
    const int i = j & 7;
    const int row = i * 16 + (lane >> 2);
    const int chunk = (lane & 3) ^ ((row >> 1) & 3);
    const unsigned short* base = (tile == 0) ? Ah : (tile == 1) ? Al
                               : (tile == 2) ? Bh : Bl;
    const int ld = (tile < 2) ? lda : ldb;
    const int grow = (tile < 2) ? (bm + row) : min(bn + row, N - 1);
    sp[q] = base + (size_t)grow * ld + chunk * 8;
    dpo[q] = tile * 4096 + i * 512 + lane * 8;
  }

  int offA[4], offB[4];
#pragma unroll
  for (int i = 0; i < 4; ++i) {
    offA[i] = frag_off(0,    wm + i * 16 + fr, kg);
    offB[i] = frag_off(8192, wn + i * 16 + fr, kg);
  }

  f32x4 acc[4][4] = {};
#pragma unroll
  for (int q = 0; q < 8; ++q) gl_lds16(sp[q], sm + dpo[q]);

  int cur = 0;
  for (int k0 = 0; k0 < klen; k0 += 32) {
    __syncthreads();                     // buf[cur] staged (vmcnt drained)
    if (k0 + 32 < klen) {
      unsigned short* nb = sm + ((cur ^ 1) << 14);
#pragma unroll
      for (int q = 0; q < 8; ++q) { sp[q] += 32; gl_lds16(sp[q], nb + dpo[q]); }
    }
    const unsigned short* s = sm + (cur << 14);
    bf16x8 fbh[4], fbl[4];
#pragma unroll
    for (int ni = 0; ni < 4; ++ni) {
      fbh[ni] = *reinterpret_cast<const bf16x8*>(s + offB[ni]);
      fbl[ni] = *reinterpret_cast<const bf16x8*>(s + offB[ni] + 4096);
    }
#pragma unroll
    for (int mi = 0; mi < 4; ++mi) {
      bf16x8 ah = *reinterpret_cast<const bf16x8*>(s + offA[mi]);
      bf16x8 al = *reinterpret_cast<const bf16x8*>(s + offA[mi] + 4096);
#pragma unroll
      for (int ni = 0; ni < 4; ++ni) {
        acc[mi][ni] = __builtin_amdgcn_mfma_f32_16x16x32_bf16(ah, fbh[ni], acc[mi][ni], 0, 0, 0);
        acc[mi][ni] = __builtin_amdgcn_mfma_f32_16x16x32_bf16(ah, fbl[ni], acc[mi][ni], 0, 0, 0);
        acc[mi][ni] = __builtin_amdgcn_mfma_f32_16x16x32_bf16(al, fbh[ni], acc[mi][ni], 0, 0, 0);
      }
    }
    cur ^= 1;
  }

#pragma unroll
  for (int mi = 0; mi < 4; ++mi) {
#pragma unroll
    for (int ni = 0; ni < 4; ++ni) {
      const int col = bn + wn + ni * 16 + fr;
      if (col >= N) continue;
      const int row0 = bm + wm + mi * 16 + kg * 4;
      const float bv = bias ? bias[col] : 0.f;
#pragma unroll
      for (int r = 0; r < 4; ++r) {
        float v = acc[mi][ni][r] + bv;
        if (relu) v = fmaxf(v, 0.f);
        C[(size_t)(row0 + r) * ldc + col] = v;
      }
    }
  }
}

// ---- wrapper: partial-K via blockIdx.z
__global__ __launch_bounds__(256) void gemm_x3_pre(
    const unsigned short* __restrict__ Ah, const unsigned short* __restrict__ Al,
    int lda,
    const unsigned short* __restrict__ Bh, const unsigned short* __restrict__ Bl,
    int ldb,
    const float* __restrict__ bias, float* __restrict__ C, int ldc,
    int M, int N, int Ktot, int kslice, int relu)
{
  __shared__ unsigned short sm[32768];
  const int z = blockIdx.z;
  const int koff = z * kslice;
  const int klen = min(kslice, Ktot - koff);
  float* Cz = C + (size_t)z * (size_t)M * (size_t)N;
  gemm128_dbuf(sm, Ah + koff, Al + koff, lda, Bh + koff, Bl + koff, ldb,
               bias, Cz, ldc, N, klen, relu,
               blockIdx.x * 128, blockIdx.y * 128);
}

// ---- variant 2: 128x64 tile, bias+relu+bf16-split epilogue, dbuf.
__global__ __launch_bounds__(256) void gemm_x3_n64(
    const unsigned short* __restrict__ Ah, const unsigned short* __restrict__ Al,
    int lda,
    const unsigned short* __restrict__ Bh, const unsigned short* __restrict__ Bl,
    int ldb,
    const float* __restrict__ bias,
    unsigned short* __restrict__ Ch, unsigned short* __restrict__ Cl,
    int ldc, int K, int relu)
{
  __shared__ unsigned short sm[24576];   // 2 x (Ah@0 Al@4096 Bh@8192 Bl@10240)

  const int t = threadIdx.x;
  const int bm = blockIdx.x * 128;
  const int bn = blockIdx.y * 64;
  const int lane = t & 63, wave = t >> 6;
  const int wm = (wave >> 1) * 64, wn = (wave & 1) * 32;
  const int fr = lane & 15, kg = lane >> 4;

  const unsigned short* sp[6];
  int dpo[6];
#pragma unroll
  for (int q = 0; q < 6; ++q) {
    const int j = wave + 4 * q;
    int tile, i;
    if (j < 8)       { tile = 0; i = j; }
    else if (j < 16) { tile = 1; i = j - 8; }
    else if (j < 20) { tile = 2; i = j - 16; }
    else             { tile = 3; i = j - 20; }
    const int row = i * 16 + (lane >> 2);
    const int chunk = (lane & 3) ^ ((row >> 1) & 3);
    const unsigned short* base = (tile == 0) ? Ah : (tile == 1) ? Al
                               : (tile == 2) ? Bh : Bl;
    const int ld = (tile < 2) ? lda : ldb;
    const int grow = (tile < 2) ? (bm + row) : (bn + row);
    const int tb = (tile == 0) ? 0 : (tile == 1) ? 4096 : (tile == 2) ? 8192 : 10240;
    sp[q] = base + (size_t)grow * ld + chunk * 8;
    dpo[q] = tb + i * 512 + lane * 8;
  }

  int offA[4], offB[2];
#pragma unroll
  for (int i = 0; i < 4; ++i) offA[i] = frag_off(0, wm + i * 16 + fr, kg);
#pragma unroll
  for (int i = 0; i < 2; ++i) offB[i] = frag_off(8192, wn + i * 16 + fr, kg);

  f32x4 acc[4][2] = {};
#pragma unroll
  for (int q = 0; q < 6; ++q) gl_lds16(sp[q], sm + dpo[q]);

  int cur = 0;
  for (int k0 = 0; k0 < K; k0 += 32) {
    __syncthreads();
    if (k0 + 32 < K) {
      unsigned short* nb = sm + (cur ^ 1) * 12288;
#pragma unroll
      for (int q = 0; q < 6; ++q) { sp[q] += 32; gl_lds16(sp[q], nb + dpo[q]); }
    }
    const unsigned short* s = sm + cur * 12288;
    bf16x8 fbh[2], fbl[2];
#pragma unroll
    for (int ni = 0; ni < 2; ++ni) {
      fbh[ni] = *reinterpret_cast<const bf16x8*>(s + offB[ni]);
      fbl[ni] = *reinterpret_cast<const bf16x8*>(s + offB[ni] + 2048);
    }
#pragma unroll
    for (int mi = 0; mi < 4; ++mi) {
      bf16x8 ah = *reinterpret_cast<const bf16x8*>(s + offA[mi]);
      bf16x8 al = *reinterpret_cast<const bf16x8*>(s + offA[mi] + 4096);
#pragma unroll
      for (int ni = 0; ni < 2; ++ni) {
        acc[mi][ni] = __builtin_amdgcn_mfma_f32_16x16x32_bf16(ah, fbh[ni], acc[mi][ni], 0, 0, 0);
        acc[mi][ni] = __builtin_amdgcn_mfma_f32_16x16x32_bf16(ah, fbl[ni], acc[mi][ni], 0, 0, 0);
        acc[mi][ni] = __builtin_amdgcn_mfma_f32_16x16x32_bf16(al, fbh[ni], acc[mi][ni], 0, 0, 0);
      }
    }
    cur ^= 1;
  }

#pragma unroll
  for (int mi = 0; mi < 4; ++mi) {
#pragma unroll
    for (int ni = 0; ni < 2; ++ni) {
      const int col = bn + wn + ni * 16 + fr;
      const int row0 = bm + wm + mi * 16 + kg * 4;
      const float bv = bias[col];
#pragma unroll
      for (int r = 0; r < 4; ++r) {
        float v = acc[mi][ni][r] + bv;
        if (relu) v = fmaxf(v, 0.f);
        const size_t o = (size_t)(row0 + r) * ldc + col;
        unsigned short h = f2bf(v);
        Ch[o] = h;
        Cl[o] = f2bf(v - bf2f(h));
      }
    }
  }
}

// ---- variant 3: embed GEMM, fp32 A reg-prefetched + split, B via gl_lds.
__global__ __launch_bounds__(256) void gemm_x3_embed(
    const float* __restrict__ A0, const float* __restrict__ A1,
    const float* __restrict__ A2, const float* __restrict__ A3,
    const unsigned short* __restrict__ EW, const float* __restrict__ b_embed,
    float* __restrict__ TAN)
{
  __shared__ unsigned short sm[32768];   // 2 x (Ah@0 Al@4096 Bh@8192 Bl@12288)

  const int c = blockIdx.z;
  const float* A = (c == 0) ? A0 : (c == 1) ? A1 : (c == 2) ? A2 : A3;
  const unsigned short* Bh = EW + (size_t)c * 262144u;
  const unsigned short* Bl = Bh + 131072u;
  const float* bias = b_embed + c * 256;
  float* C = TAN + (size_t)c * 15360 * 256;

  const int t = threadIdx.x;
  const int bm = blockIdx.x * 128;
  const int bn = blockIdx.y * 128;
  const int lane = t & 63, wave = t >> 6;
  const int wm = (wave >> 1) * 64, wn = (wave & 1) * 64;
  const int fr = lane & 15, kg = lane >> 4;

  const unsigned short* sp[4];
  int dpo[4];
#pragma unroll
  for (int q = 0; q < 4; ++q) {
    const int j = wave + 4 * q;
    const int tile = j >> 3;            // 0 Bh, 1 Bl
    const int i = j & 7;
    const int row = i * 16 + (lane >> 2);
    const int chunk = (lane & 3) ^ ((row >> 1) & 3);
    const unsigned short* base = tile ? Bl : Bh;
    sp[q] = base + (size_t)(bn + row) * 512 + chunk * 8;
    dpo[q] = 8192 + tile * 4096 + i * 512 + lane * 8;
  }

  const int arow = t >> 1, khalf = t & 1;
  const float* aptr = A + (size_t)(bm + arow) * 504 + khalf * 16;
  const int axor = (arow >> 1) & 3;
  const int woff0 = arow * 32 + (((khalf * 2)     ^ axor) << 3);
  const int woff1 = arow * 32 + (((khalf * 2 + 1) ^ axor) << 3);

  int offA[4], offB[4];
#pragma unroll
  for (int i = 0; i < 4; ++i) {
    offA[i] = frag_off(0,    wm + i * 16 + fr, kg);
    offB[i] = frag_off(8192, wn + i * 16 + fr, kg);
  }

  float4 fa0, fa1, fa2, fa3;
  const float4 zf = make_float4(0.f, 0.f, 0.f, 0.f);
  auto loadA = [&](int k0) {
    const int gk = k0 + khalf * 16;
    fa0 = (gk      < 504) ? *reinterpret_cast<const float4*>(aptr + k0)      : zf;
    fa1 = (gk + 4  < 504) ? *reinterpret_cast<const float4*>(aptr + k0 + 4)  : zf;
    fa2 = (gk + 8  < 504) ? *reinterpret_cast<const float4*>(aptr + k0 + 8)  : zf;
    fa3 = (gk + 12 < 504) ? *reinterpret_cast<const float4*>(aptr + k0 + 12) : zf;
  };

  f32x4 acc[4][4] = {};
  loadA(0);
#pragma unroll
  for (int q = 0; q < 4; ++q) gl_lds16(sp[q], sm + dpo[q]);

  int cur = 0;
  for (int k0 = 0; k0 < 512; k0 += 32) {
    {  // convert prefetched A regs -> split bf16 -> LDS buf[cur]
      unsigned short* ab = sm + (cur << 14);
      float xs[16] = {fa0.x, fa0.y, fa0.z, fa0.w, fa1.x, fa1.y, fa1.z, fa1.w,
                      fa2.x, fa2.y, fa2.z, fa2.w, fa3.x, fa3.y, fa3.z, fa3.w};
      unsigned short ah[16], al[16];
#pragma unroll
      for (int i = 0; i < 16; ++i) {
        unsigned short h = f2bf(xs[i]);
        ah[i] = h;
        al[i] = f2bf(xs[i] - bf2f(h));
      }
      bf16x8 p;
#pragma unroll
      for (int i = 0; i < 8; ++i) p[i] = (short)ah[i];
      *reinterpret_cast<bf16x8*>(ab + woff0) = p;
#pragma unroll
      for (int i = 0; i < 8; ++i) p[i] = (short)ah[8 + i];
      *reinterpret_cast<bf16x8*>(ab + woff1) = p;
#pragma unroll
      for (int i = 0; i < 8; ++i) p[i] = (short)al[i];
      *reinterpret_cast<bf16x8*>(ab + 4096 + woff0) = p;
#pragma unroll
      for (int i = 0; i < 8; ++i) p[i] = (short)al[8 + i];
      *reinterpret_cast<bf16x8*>(ab + 4096 + woff1) = p;
    }
    __syncthreads();                     // drains A ds_writes + B gl_lds
    if (k0 + 32 < 512) {
      loadA(k0 + 32);                    // reg prefetch next A
      unsigned short* nb = sm + ((cur ^ 1) << 14);
#pragma unroll
      for (int q = 0; q < 4; ++q) { sp[q] += 32; gl_lds16(sp[q], nb + dpo[q]); }
    }
    const unsigned short* s = sm + (cur << 14);
    bf16x8 fbh[4], fbl[4];
#pragma unroll
    for (int ni = 0; ni < 4; ++ni) {
      fbh[ni] = *reinterpret_cast<const bf16x8*>(s + offB[ni]);
      fbl[ni] = *reinterpret_cast<const bf16x8*>(s + offB[ni] + 4096);
    }
#pragma unroll
    for (int mi = 0; mi < 4; ++mi) {
      bf16x8 ah = *reinterpret_cast<const bf16x8*>(s + offA[mi]);
      bf16x8 al = *reinterpret_cast<const bf16x8*>(s + offA[mi] + 4096);
#pragma unroll
      for (int ni = 0; ni < 4; ++ni) {
        acc[mi][ni] = __builtin_amdgcn_mfma_f32_16x16x32_bf16(ah, fbh[ni], acc[mi][ni], 0, 0, 0);
        acc[mi][ni] = __builtin_amdgcn_mfma_f32_16x16x32_bf16(ah, fbl[ni], acc[mi][ni], 0, 0, 0);
        acc[mi][ni] = __builtin_amdgcn_mfma_f32_16x16x32_bf16(al, fbh[ni], acc[mi][ni], 0, 0, 0);
      }
    }
    cur ^= 1;
  }

#pragma unroll
  for (int mi = 0; mi < 4; ++mi) {
#pragma unroll
    for (int ni = 0; ni < 4; ++ni) {
      const int col = bn + wn + ni * 16 + fr;
      const int row0 = bm + wm + mi * 16 + kg * 4;
      const float bv = bias[col];
#pragma unroll
      for (int r = 0; r < 4; ++r)
        C[(size_t)(row0 + r) * 256 + col] = acc[mi][ni][r] + bv;
    }
  }
}

// ------------------------------------- LayerNorm + expmap0 -> Z (wave/row)
__global__ __launch_bounds__(256) void ln_expmap0_k(
    const float* __restrict__ TAN, const float* __restrict__ gamma,
    const float* __restrict__ beta, float* __restrict__ Z)
{
  const int row = blockIdx.x * 4 + (threadIdx.x >> 6);   // b*30 + n
  const int lane = threadIdx.x & 63;
  const int b = row / 30;
  const int n = row % 30;

  float4 tc[4];
  float4 ts = make_float4(0.f, 0.f, 0.f, 0.f);
#pragma unroll
  for (int c = 0; c < 4; ++c) {
    float4 x = *reinterpret_cast<const float4*>(
        TAN + ((size_t)c * 15360 + row) * 256 + lane * 4);
    float mu = wave_sum(x.x + x.y + x.z + x.w) * (1.f / 256.f);
    float4 xm = make_float4(x.x - mu, x.y - mu, x.z - mu, x.w - mu);
    float var = wave_sum(xm.x * xm.x + xm.y * xm.y + xm.z * xm.z + xm.w * xm.w)
                * (1.f / 256.f);
    float rs = rsqrtf(var + 1e-5f);
    float4 g = *reinterpret_cast<const float4*>(gamma + c * 256 + lane * 4);
    float4 be = *reinterpret_cast<const float4*>(beta + c * 256 + lane * 4);
    float4 tv = make_float4(xm.x * rs * g.x + be.x, xm.y * rs * g.y + be.y,
                            xm.z * rs * g.z + be.z, xm.w * rs * g.w + be.w);
    tc[c] = tv;
    ts.x += tv.x; ts.y += tv.y; ts.z += tv.z; ts.w += tv.w;
  }
#pragma unroll
  for (int g5 = 0; g5 < 5; ++g5) {
    float4 v = (g5 == 0) ? ts : tc[g5 - 1];
    float n2 = wave_sum(v.x * v.x + v.y * v.y + v.z * v.z + v.w * v.w);
    float nn = fmaxf(sqrtf(n2), EPS_F);
    float th = tanhf(nn);
    float w = th / nn;
    if (th > MAX_NORM_F) w *= MAX_NORM_F / fmaxf(th, EPS_F);
    float4 o = make_float4(v.x * w, v.y * w, v.z * w, v.w * w);
    *reinterpret_cast<float4*>(
        Z + (((size_t)g5 * 512 + b) * 38 + n) * 256 + lane * 4) = o;
  }
}

// ------------------------------------------------ per-pair logmap (1 wave)
__device__ __forceinline__ float4 pair_log(const float* zr, int c, int lane) {
  float4 x = *reinterpret_cast<const float4*>(zr + (size_t)c * 256 + lane * 4);
  float4 y = *reinterpret_cast<const float4*>(zr + (size_t)(c + 1) * 256 + lane * 4);
  float x2 = wave_sum(x.x * x.x + x.y * x.y + x.z * x.z + x.w * x.w);
  float y2 = wave_sum(y.x * y.x + y.y * y.y + y.z * y.z + y.w * y.w);
  float xy = wave_sum(x.x * y.x + x.y * y.y + x.z * y.z + x.w * y.w);
  float a  = 1.f - 2.f * xy + y2;
  float bb = 1.f - x2;
  float den = fmaxf(1.f - 2.f * xy + x2 * y2, EPS_F);
  float inv = 1.f / den;
  float4 u;
  u.x = (bb * y.x - a * x.x) * inv;
  u.y = (bb * y.y - a * x.y) * inv;
  u.z = (bb * y.z - a * x.z) * inv;
  u.w = (bb * y.w - a * x.w) * inv;
  float u2 = wave_sum(u.x * u.x + u.y * u.y + u.z * u.z + u.w * u.w);
  float un = fmaxf(sqrtf(u2), EPS_F);
  float coef = fmaxf(1.f - x2, EPS_F) * atanhf(fminf(un, 1.f - 1e-7f)) / un;
  float4 o;
  o.x = coef * u.x; o.y = coef * u.y; o.z = coef * u.z; o.w = coef * u.w;
  return o;
}

__device__ __forceinline__ float4 logmap0_col(const float* zr, int c, int lane) {
  float4 z = *reinterpret_cast<const float4*>(zr + (size_t)c * 256 + lane * 4);
  float z2 = wave_sum(z.x * z.x + z.y * z.y + z.z * z.z + z.w * z.w);
  float nz = fmaxf(sqrtf(z2), EPS_F);
  float cc = atanhf(fminf(nz, 1.f - 1e-7f)) / nz;
  float4 o;
  o.x = cc * z.x; o.y = cc * z.y; o.z = cc * z.z; o.w = cc * z.w;
  return o;
}

// -------------------------- velocity (t=0 full window) + feat
__global__ __launch_bounds__(256) void vel_feat_inc_k(
    const float* __restrict__ Z, unsigned short* __restrict__ Fh,
    unsigned short* __restrict__ Fl, float* __restrict__ VSUM, int t)
{
  const int r = blockIdx.x * 4 + (threadIdx.x >> 6);
  const int lane = threadIdx.x & 63;
  const float* zr = Z + (size_t)r * 38 * 256;

  float4 vs = make_float4(0.f, 0.f, 0.f, 0.f);
#pragma unroll 1
  for (int j = 0; j < 29; ++j) {
    float4 p = pair_log(zr, t + j, lane);
    vs.x += p.x; vs.y += p.y; vs.z += p.z; vs.w += p.w;
  }
  *reinterpret_cast<float4*>(VSUM + (size_t)r * 256 + lane * 4) = vs;

  float4 fl = logmap0_col(zr, t + 29, lane);   // z_last
  float4 fp = logmap0_col(zr, t + 28, lane);   // z_prev
  const size_t fb = (size_t)r * 768 + lane * 4;
  store_split4(Fh, Fl, fb, fl);
  store_split4(Fh, Fl, fb + 256, fp);
  const float s29 = 1.f / 29.f;
  float4 o;
  o.x = vs.x * s29; o.y = vs.y * s29; o.z = vs.z * s29; o.w = vs.w * s29;
  store_split4(Fh, Fl, fb + 512, o);
}

// --------- fused: z_next = expmap(z_last, sum VP + b3); then (if t<7)
// incremental velocity + FEAT for step t+1 (z_next, z_last in registers).
__global__ __launch_bounds__(256) void expmap_vel_fused_k(
    float* __restrict__ Z, const float* __restrict__ VP,
    const float* __restrict__ b3, unsigned short* __restrict__ Fh,
    unsigned short* __restrict__ Fl, float* __restrict__ VSUM, int t)
{
  const int r = blockIdx.x * 4 + (threadIdx.x >> 6);
  const int lane = threadIdx.x & 63;
  float* zr = Z + (size_t)r * 38 * 256;
  float4 x = *reinterpret_cast<const float4*>(zr + (size_t)(t + 29) * 256 + lane * 4);
  float4 v = *reinterpret_cast<const float4*>(b3 + lane * 4);
#pragma unroll
  for (int p = 0; p < 8; ++p) {
    float4 a = *reinterpret_cast<const float4*>(
        VP + (size_t)p * 655360u + (size_t)r * 256 + lane * 4);
    v.x += a.x; v.y += a.y; v.z += a.z; v.w += a.w;
  }
  float x2 = wave_sum(x.x * x.x + x.y * x.y + x.z * x.z + x.w * x.w);
  float v2 = wave_sum(v.x * v.x + v.y * v.y + v.z * v.z + v.w * v.w);
  float xv = wave_sum(x.x * v.x + x.y * v.y + x.z * v.z + x.w * v.w);

  float vn = fmaxf(sqrtf(v2), EPS_F);
  float lamx = 2.f / fmaxf(1.f - x2, EPS_F);
  float s = tanhf(0.5f * lamx * vn) / vn;
  float xy = s * xv;
  float y2 = s * s * v2;
  float a  = 1.f + 2.f * xy + y2;
  float bb = 1.f - x2;
  float den = fmaxf(1.f + 2.f * xy + x2 * y2, EPS_F);
  float inv = 1.f / den;
  float4 res;
  res.x = (a * x.x + bb * s * v.x) * inv;
  res.y = (a * x.y + bb * s * v.y) * inv;
  res.z = (a * x.z + bb * s * v.z) * inv;
  res.w = (a * x.w + bb * s * v.w) * inv;
  float r2 = wave_sum(res.x * res.x + res.y * res.y + res.z * res.z + res.w * res.w);
  float rn = sqrtf(r2);
  if (rn > MAX_NORM_F) {
    float sc = MAX_NORM_F / fmaxf(rn, EPS_F);
    res.x *= sc; res.y *= sc; res.z *= sc; res.w *= sc;
    r2 = MAX_NORM_F * MAX_NORM_F;
    rn = MAX_NORM_F;
  }
  *reinterpret_cast<float4*>(zr + (size_t)(t + 30) * 256 + lane * 4) = res;

  if (t < 7) {
    // pm = pair (t, t+1) leaving the window; pp = pair (x, res) entering.
    float4 pm = pair_log(zr, t, lane);
    float xyn = wave_sum(x.x * res.x + x.y * res.y + x.z * res.z + x.w * res.w);
    float an  = 1.f - 2.f * xyn + r2;
    float bbn = 1.f - x2;
    float denn = fmaxf(1.f - 2.f * xyn + x2 * r2, EPS_F);
    float invn = 1.f / denn;
    float4 u;
    u.x = (bbn * res.x - an * x.x) * invn;
    u.y = (bbn * res.y - an * x.y) * invn;
    u.z = (bbn * res.z - an * x.z) * invn;
    u.w = (bbn * res.w - an * x.w) * invn;
    float u2 = wave_sum(u.x * u.x + u.y * u.y + u.z * u.z + u.w * u.w);
    float un = fmaxf(sqrtf(u2), EPS_F);
    float coef = fmaxf(1.f - x2, EPS_F) * atanhf(fminf(un, 1.f - 1e-7f)) / un;
    float4 vs = *reinterpret_cast<const float4*>(VSUM + (size_t)r * 256 + lane * 4);
    vs.x += coef * u.x - pm.x; vs.y += coef * u.y - pm.y;
    vs.z += coef * u.z - pm.z; vs.w += coef * u.w - pm.w;
    *reinterpret_cast<float4*>(VSUM + (size_t)r * 256 + lane * 4) = vs;

    // FEAT for step t+1: z_last = res, z_prev = x, vel = vs/29
    float rnp = fmaxf(rn, EPS_F);
    float cl = atanhf(fminf(rnp, 1.f - 1e-7f)) / rnp;
    float nx = fmaxf(sqrtf(x2), EPS_F);
    float cp = atanhf(fminf(nx, 1.f - 1e-7f)) / nx;
    const size_t fb = (size_t)r * 768 + lane * 4;
    float4 o;
    o.x = cl * res.x; o.y = cl * res.y; o.z = cl * res.z; o.w = cl * res.w;
    store_split4(Fh, Fl, fb, o);
    o.x = cp * x.x; o.y = cp * x.y; o.z = cp * x.z; o.w = cp * x.w;
    store_split4(Fh, Fl, fb + 256, o);
    const float s29 = 1.f / 29.f;
    o.x = vs.x * s29; o.y = vs.y * s29; o.z = vs.z * s29; o.w = vs.w * s29;
    store_split4(Fh, Fl, fb + 512, o);
  }
}

// -------------------------- logmap0 over appended cols, split bf16 out
__global__ __launch_bounds__(256) void logmap0_rows_k(
    const float* __restrict__ Z, unsigned short* __restrict__ Uh,
    unsigned short* __restrict__ Ul)
{
  const int q = blockIdx.x * 4 + (threadIdx.x >> 6);
  const int lane = threadIdx.x & 63;
  const int r = q >> 3;
  const int tt = q & 7;
  float4 o = logmap0_col(Z + (size_t)r * 38 * 256, 30 + tt, lane);
  store_split4(Uh, Ul, (size_t)q * 256 + lane * 4, o);
}

// ---------------------------------------------------------------- launcher
extern "C" void kernel_launch(void* const* d_in, const int* in_sizes, int n_in,
                              void* d_out, int out_size, void* d_ws, size_t ws_size,
                              hipStream_t stream)
{
  const float* c0 = (const float*)d_in[0];
  const float* c1 = (const float*)d_in[1];
  const float* c2 = (const float*)d_in[2];
  const float* c3 = (const float*)d_in[3];
  const float* W_embed = (const float*)d_in[4];
  const float* b_embed = (const float*)d_in[5];
  const float* ln_g    = (const float*)d_in[6];
  const float* ln_b    = (const float*)d_in[7];
  const float* W1 = (const float*)d_in[8];
  const float* b1 = (const float*)d_in[9];
  const float* W2 = (const float*)d_in[10];
  const float* b2 = (const float*)d_in[11];
  const float* W3 = (const float*)d_in[12];
  const float* b3 = (const float*)d_in[13];
  const float* W_out = (const float*)d_in[14];
  const float* b_out = (const float*)d_in[15];
  float* out = (float*)d_out;
  float* ws  = (float*)d_ws;

  // ---- ws layout (floats). Peak = Z(24,903,680) + R(15,728,640) = 162.5 MB.
  float* Z = ws;
  float* TAN = ws + 24903680u;                      // R region = TAN in stage A
  unsigned short* Rs = (unsigned short*)(ws + 24903680u);
  unsigned short* W1h = Rs;                         // [1024][768]
  unsigned short* W1l = Rs + 786432u;
  unsigned short* W2h = Rs + 1572864u;              // [1024][1024]
  unsigned short* W2l = Rs + 2621440u;
  unsigned short* W3h = Rs + 3670016u;              // [256][1024]
  unsigned short* W3l = Rs + 3932160u;
  unsigned short* Woh = Rs + 4194304u;              // [504][256]
  unsigned short* Wol = Rs + 4323328u;
  unsigned short* FEATh = Rs + 4452352u;            // [2560][768]
  unsigned short* FEATl = Rs + 6418432u;
  unsigned short* H1h = Rs + 8384512u;              // [2560][1024]
  unsigned short* H1l = Rs + 11005952u;
  unsigned short* H2h = Rs + 13627392u;             // [2560][1024]
  unsigned short* H2l = Rs + 16248832u;             // ends @ short 18,870,272
  float* VP   = ws + 34338816u;                     // 8 x 2560*256 parts
  float* VSUM = ws + 39581696u;                     // 2560*256
  unsigned short* Uh = Rs + 4452352u;               // stage C, reuses FEAT/H1
  unsigned short* Ul = Rs + 9695232u;

  // ---- d_out scratch: embed weights (stage A only; final GEMM overwrites).
  unsigned short* EW = (unsigned short*)d_out;      // 4 x (h 131072 | l 131072)

  dim3 blk(256);

  // Stage A: embed weight split -> embed GEMM -> LN+expmap0
  {
    WS4 d;
    for (int c = 0; c < 4; ++c) {
      d.W[c] = W_embed + (size_t)c * 504 * 256;
      d.Th[c] = EW + (size_t)c * 262144u;
      d.Tl[c] = EW + (size_t)c * 262144u + 131072u;
      d.K[c] = 504; d.N[c] = 256; d.Kp[c] = 512;
    }
    wsplit_all_k<<<dim3(4, 8, 4), blk, 0, stream>>>(d);
  }
  gemm_x3_embed<<<dim3(120, 2, 4), blk, 0, stream>>>(
      c0, c1, c2, c3, EW, b_embed, TAN);
  ln_expmap0_k<<<dim3(3840), blk, 0, stream>>>(TAN, ln_g, ln_b, Z);

  // MLP/out weight splits in one launch (TAN dead now)
  {
    WS4 d;
    d.W[0] = W1;    d.Th[0] = W1h; d.Tl[0] = W1l; d.K[0] = 768;  d.N[0] = 1024; d.Kp[0] = 768;
    d.W[1] = W2;    d.Th[1] = W2h; d.Tl[1] = W2l; d.K[1] = 1024; d.N[1] = 1024; d.Kp[1] = 1024;
    d.W[2] = W3;    d.Th[2] = W3h; d.Tl[2] = W3l; d.K[2] = 1024; d.N[2] = 256;  d.Kp[2] = 1024;
    d.W[3] = W_out; d.Th[3] = Woh; d.Tl[3] = Wol; d.K[3] = 256;  d.N[3] = 504;  d.Kp[3] = 256;
    wsplit_all_k<<<dim3(16, 16, 4), blk, 0, stream>>>(d);
  }

  // Stage B: 8 recurrent steps (velocity/feat fused into expmap)
  vel_feat_inc_k<<<dim3(640), blk, 0, stream>>>(Z, FEATh, FEATl, VSUM, 0);
  for (int t = 0; t < 8; ++t) {
    gemm_x3_n64<<<dim3(20, 16), blk, 0, stream>>>(
        FEATh, FEATl, 768, W1h, W1l, 768, b1, H1h, H1l, 1024, 768, 1);
    gemm_x3_n64<<<dim3(20, 16), blk, 0, stream>>>(
        H1h, H1l, 1024, W2h, W2l, 1024, b2, H2h, H2l, 1024, 1024, 1);
    gemm_x3_pre<<<dim3(20, 2, 8), blk, 0, stream>>>(
        H2h, H2l, 1024, W3h, W3l, 1024, nullptr, VP, 256,
        2560, 256, 1024, 128, 0);
    expmap_vel_fused_k<<<dim3(640), blk, 0, stream>>>(
        Z, VP, b3, FEATh, FEATl, VSUM, t);
  }

  // Stage C: logmap0 -> final projection into d_out
  logmap0_rows_k<<<dim3(5120), blk, 0, stream>>>(Z, Uh, Ul);
  gemm_x3_pre<<<dim3(160, 4, 1), blk, 0, stream>>>(
      Uh, Ul, 256, Woh, Wol, 256, b_out, out, 504,
      20480, 504, 256, 256, 0);
}